// Round 1
// baseline (1372.771 us; speedup 1.0000x reference)
//
#include <hip/hip_runtime.h>

#define N_NODES 100000
#define N_PAD   100096
#define N_EDGES 1600000
#define NGRAPH  64
#define NHEAD   8
#define NCH     16
#define HID     128
#define IN0     288
#define NREL    51
#define EMB     256
#define NBBOX   32
#define NEG_SLOPE 0.2f
#define EPS_BN  1e-5f
#define AGG_BLOCKS 1280
#define POOL_BLOCKS 128

typedef unsigned int uint;
typedef unsigned short ushort;

typedef __bf16 bf16_t;
typedef bf16_t bfx8 __attribute__((ext_vector_type(8)));
typedef float  fx4  __attribute__((ext_vector_type(4)));

__device__ __forceinline__ ushort f2bf(float f) {
  uint u = __float_as_uint(f);
  u += 0x7fffu + ((u >> 16) & 1u);
  return (ushort)(u >> 16);
}
__device__ __forceinline__ float bf2f(uint u) { return __uint_as_float(u << 16); }

// ---------------- prep: weight transpose->bf16, ee tables, bias concat ----------------
__global__ void se_prep(const float* __restrict__ Wl0, const float* __restrict__ Wr0,
                        const float* __restrict__ WlS, const float* __restrict__ WrS,
                        const float* __restrict__ rel_emb, const float* __restrict__ We0,
                        const float* __restrict__ WeS,
                        const float* __restrict__ bl0, const float* __restrict__ br0,
                        const float* __restrict__ blS, const float* __restrict__ brS,
                        ushort* __restrict__ W0T, ushort* __restrict__ WST,
                        float* __restrict__ eetab, float* __restrict__ biascat) {
  int i = blockIdx.x * 256 + threadIdx.x;
  if (i < 256 * IN0) {                       // W0T[j][k] = Wl0|Wr0 [k][j]
    int j = i / IN0, k = i - j * IN0;
    float v = (j < 128) ? Wl0[k * 128 + j] : Wr0[k * 128 + (j - 128)];
    W0T[j * IN0 + k] = f2bf(v);
    return;
  }
  i -= 256 * IN0;
  if (i < 2 * 256 * HID) {                   // WST[l][j][k]
    int li = i >> 15;
    int rem = i & 32767;
    int j = rem >> 7, k = rem & 127;
    float v = (j < 128) ? WlS[(li * 128 + k) * 128 + j] : WrS[(li * 128 + k) * 128 + (j - 128)];
    WST[(li * 256 + j) * 128 + k] = f2bf(v);
    return;
  }
  i -= 2 * 256 * HID;
  if (i < 3 * NREL * HID) {                  // eetab[l][r][j] = sum_c rel[r][c]*We_l[c][j]
    int li = i / (NREL * HID);
    int rem = i - li * (NREL * HID);
    int r = rem >> 7, j = rem & 127;
    const float* We = (li == 0) ? We0 : (WeS + (li - 1) * NCH * HID);
    float s = 0.f;
#pragma unroll
    for (int c = 0; c < NCH; c++) s += rel_emb[r * NCH + c] * We[c * HID + j];
    eetab[li * (NREL * HID) + rem] = s;
    return;
  }
  i -= 3 * NREL * HID;
  if (i < 3 * 256) {                         // biascat[l][256] = bl|br
    int li = i >> 8, j = i & 255;
    const float* bl = (li == 0) ? bl0 : (blS + (li - 1) * HID);
    const float* br = (li == 0) ? br0 : (brS + (li - 1) * HID);
    biascat[i] = (j < 128) ? bl[j] : br[j - 128];
  }
}

// ---------------- build x = [tok_emb[tok] | bbox@W+b] as bf16, zero-pad rows ----------------
__global__ void se_build_x(const int* __restrict__ tok_id, const float* __restrict__ bbox,
                           const float* __restrict__ tok_emb, const float* __restrict__ bbox_W,
                           const float* __restrict__ bbox_b, ushort* __restrict__ x) {
  int idx = blockIdx.x * 256 + threadIdx.x;
  if (idx >= N_PAD * IN0) return;
  int n = idx / IN0, c = idx - n * IN0;
  float v = 0.f;
  if (n < N_NODES) {
    if (c < EMB) {
      v = tok_emb[tok_id[n] * EMB + c];
    } else {
      int j = c - EMB;
      v = bbox_b[j];
#pragma unroll
      for (int k = 0; k < 4; k++) v += bbox[n * 4 + k] * bbox_W[k * NBBOX + j];
    }
  }
  x[idx] = f2bf(v);
}

// ---------------- CSR build ----------------
__global__ void se_hist(const int* __restrict__ ei, int* __restrict__ deg) {
  int e = blockIdx.x * 256 + threadIdx.x;
  if (e < N_EDGES) atomicAdd(&deg[ei[N_EDGES + e]], 1);
}
__global__ __launch_bounds__(1024) void se_scanA(const int* __restrict__ deg,
                                                 int* __restrict__ offs, int* __restrict__ bsum) {
  __shared__ int s[1024];
  const int tid = threadIdx.x;
  const int i = blockIdx.x * 1024 + tid;
  int v = (i < N_NODES) ? deg[i] : 0;
  s[tid] = v;
  __syncthreads();
  for (int d = 1; d < 1024; d <<= 1) {
    int t = (tid >= d) ? s[tid - d] : 0;
    __syncthreads();
    s[tid] += t;
    __syncthreads();
  }
  if (i < N_NODES) offs[i] = s[tid] - v;
  if (tid == 1023) bsum[blockIdx.x] = s[1023];
}
__global__ void se_scanB(int* __restrict__ bsum, int nb) {
  if (threadIdx.x == 0 && blockIdx.x == 0) {
    int run = 0;
    for (int b = 0; b < nb; b++) { int t = bsum[b]; bsum[b] = run; run += t; }
  }
}
__global__ __launch_bounds__(1024) void se_scanC(int* __restrict__ offs, const int* __restrict__ bsum) {
  int i = blockIdx.x * 1024 + threadIdx.x;
  if (i < N_NODES) offs[i] += bsum[blockIdx.x];
}
__global__ void se_scatter(const int* __restrict__ ei, const int* __restrict__ eattr,
                           const int* __restrict__ offs, int* __restrict__ cur, int2* __restrict__ csr) {
  int e = blockIdx.x * 256 + threadIdx.x;
  if (e < N_EDGES) {
    int d = ei[N_EDGES + e];
    int p = offs[d] + atomicAdd(&cur[d], 1);
    csr[p] = make_int2(ei[e], eattr[e]);
  }
}

// ---------------- GEMM: C[N,256] = A[N,K] @ BT[256,K]^T + biascat, bf16 in/out, fp32 acc ----------------
template <int K>
__global__ __launch_bounds__(256) void se_gemm(const ushort* __restrict__ A,
                                               const ushort* __restrict__ BT,
                                               const float* __restrict__ bias,
                                               ushort* __restrict__ C) {
  __shared__ __align__(16) ushort As[128 * 32];
  __shared__ __align__(16) ushort Bs[128 * 32];
  const int tid = threadIdx.x;
  const int w = tid >> 6, l = tid & 63;
  const int wr = w >> 1, wc = w & 1;
  const int m0 = blockIdx.x * 128, n0 = blockIdx.y * 128;
  fx4 acc[4][4];
#pragma unroll
  for (int i = 0; i < 4; i++)
#pragma unroll
    for (int j = 0; j < 4; j++) acc[i][j] = fx4{0.f, 0.f, 0.f, 0.f};

  for (int k0 = 0; k0 < K; k0 += 32) {
#pragma unroll
    for (int ch = 0; ch < 2; ch++) {
      const int t = tid + ch * 256;          // 16B chunk id; row=t/4, col=(t%4)*8
      const int r = t >> 2, c = (t & 3) << 3;
      const ushort* ga = A + (size_t)(m0 + r) * K + (k0 + c);
      ushort* la = As + (size_t)(ch * 256 + w * 64) * 8;
      __builtin_amdgcn_global_load_lds((const __attribute__((address_space(1))) void*)ga,
                                       (__attribute__((address_space(3))) void*)la, 16, 0, 0);
      const ushort* gb = BT + (size_t)(n0 + r) * K + (k0 + c);
      ushort* lb = Bs + (size_t)(ch * 256 + w * 64) * 8;
      __builtin_amdgcn_global_load_lds((const __attribute__((address_space(1))) void*)gb,
                                       (__attribute__((address_space(3))) void*)lb, 16, 0, 0);
    }
    __syncthreads();
    bfx8 af[4], bfr[4];
#pragma unroll
    for (int i = 0; i < 4; i++) {
      af[i]  = *(const bfx8*)(As + ((wr * 64 + i * 16 + (l & 15)) * 32 + ((l >> 4) * 8)));
      bfr[i] = *(const bfx8*)(Bs + ((wc * 64 + i * 16 + (l & 15)) * 32 + ((l >> 4) * 8)));
    }
#pragma unroll
    for (int i = 0; i < 4; i++)
#pragma unroll
      for (int j = 0; j < 4; j++)
        acc[i][j] = __builtin_amdgcn_mfma_f32_16x16x32_bf16(af[i], bfr[j], acc[i][j], 0, 0, 0);
    __syncthreads();
  }
#pragma unroll
  for (int i = 0; i < 4; i++) {
    const int rbase = m0 + wr * 64 + i * 16 + ((l >> 4) << 2);
#pragma unroll
    for (int j = 0; j < 4; j++) {
      const int col = n0 + wc * 64 + j * 16 + (l & 15);
      const float bz = bias[col];
#pragma unroll
      for (int r2 = 0; r2 < 4; r2++) {
        const int row = rbase + r2;
        if (row < N_NODES) C[(size_t)row * 256 + col] = f2bf(acc[i][j][r2] + bz);
      }
    }
  }
}

// ---------------- wave-per-node online-softmax GATv2 aggregation + relu + BN partial stats ----------------
__global__ __launch_bounds__(256) void se_agg(const uint* __restrict__ xlxr,
                                              const int2* __restrict__ csr,
                                              const int* __restrict__ offs, const int* __restrict__ deg,
                                              const float* __restrict__ eetab,
                                              const float* __restrict__ att,
                                              const float* __restrict__ bias,
                                              float* __restrict__ y, float* __restrict__ partial) {
  __shared__ float2 ee[NREL * 64];
  __shared__ float bstat[256];
  const int tid = threadIdx.x, w = tid >> 6, l = tid & 63;
  for (int i = tid; i < NREL * 64; i += 256) ee[i] = ((const float2*)eetab)[i];
  bstat[tid] = 0.f;
  __syncthreads();
  const float a0 = att[(l >> 3) * NCH + ((l & 7) << 1)];
  const float a1 = att[(l >> 3) * NCH + ((l & 7) << 1) + 1];
  const float b0 = bias[2 * l], b1 = bias[2 * l + 1];
  float s0 = 0.f, s1 = 0.f, q0 = 0.f, q1 = 0.f;
  const int nw = gridDim.x * 4;
  for (int n = blockIdx.x * 4 + w; n < N_NODES; n += nw) {
    const int rs = offs[n], dg = deg[n];
    const uint xru = xlxr[n * 128 + 64 + l];
    const float xr0 = bf2f(xru & 0xffffu), xr1 = bf2f(xru >> 16);
    float mx = -INFINITY, den = 0.f, acc0 = 0.f, acc1 = 0.f;
    int2 e = make_int2(0, 0);
    uint xlu = 0u;
    if (dg > 0) { e = csr[rs]; xlu = xlxr[e.x * 128 + l]; }
    for (int i = 0; i < dg; i++) {
      int2 en = e; uint xlun = xlu;                 // depth-1 prefetch
      if (i + 1 < dg) { en = csr[rs + i + 1]; xlun = xlxr[en.x * 128 + l]; }
      const float2 ef = ee[e.y * 64 + l];
      const float xl0 = bf2f(xlu & 0xffffu), xl1 = bf2f(xlu >> 16);
      float m0 = xl0 + xr0 + ef.x;
      float m1 = xl1 + xr1 + ef.y;
      m0 = fmaxf(m0, 0.f) + NEG_SLOPE * fminf(m0, 0.f);
      m1 = fmaxf(m1, 0.f) + NEG_SLOPE * fminf(m1, 0.f);
      float s = m0 * a0 + m1 * a1;                  // per-head dot: reduce across 8 lanes
      s += __shfl_xor(s, 1);
      s += __shfl_xor(s, 2);
      s += __shfl_xor(s, 4);
      const float mn = fmaxf(mx, s);
      const float scl = __expf(mx - mn);
      const float p = __expf(s - mn);
      den = den * scl + p;
      acc0 = acc0 * scl + p * xl0;
      acc1 = acc1 * scl + p * xl1;
      mx = mn;
      e = en; xlu = xlun;
    }
    const float r = 1.f / fmaxf(den, 1e-16f);
    const float o0 = fmaxf(acc0 * r + b0, 0.f);     // + post-bias, relu
    const float o1 = fmaxf(acc1 * r + b1, 0.f);
    ((float2*)y)[n * 64 + l] = make_float2(o0, o1);
    s0 += o0; q0 += o0 * o0; s1 += o1; q1 += o1 * o1;
  }
  unsafeAtomicAdd(&bstat[2 * l], s0);
  unsafeAtomicAdd(&bstat[2 * l + 1], s1);
  unsafeAtomicAdd(&bstat[128 + 2 * l], q0);
  unsafeAtomicAdd(&bstat[128 + 2 * l + 1], q1);
  __syncthreads();
  partial[tid * AGG_BLOCKS + blockIdx.x] = bstat[tid];
}

// ---------------- BN stats finalize: mean + rsqrt(var+eps) per channel ----------------
__global__ __launch_bounds__(256) void se_stats(const float* __restrict__ partial, float* __restrict__ musig) {
  __shared__ float red[256];
  const int ch = blockIdx.x, tid = threadIdx.x;
  float s = 0.f;
  for (int i = tid; i < AGG_BLOCKS; i += 256) s += partial[ch * AGG_BLOCKS + i];
  red[tid] = s; __syncthreads();
  for (int o = 128; o > 0; o >>= 1) { if (tid < o) red[tid] += red[tid + o]; __syncthreads(); }
  const float sum = red[0]; __syncthreads();
  float q = 0.f;
  for (int i = tid; i < AGG_BLOCKS; i += 256) q += partial[(128 + ch) * AGG_BLOCKS + i];
  red[tid] = q; __syncthreads();
  for (int o = 128; o > 0; o >>= 1) { if (tid < o) red[tid] += red[tid + o]; __syncthreads(); }
  if (tid == 0) {
    const float mean = sum / (float)N_NODES;
    const float var = red[0] / (float)N_NODES - mean * mean;
    musig[ch] = mean;
    musig[128 + ch] = rsqrtf(var + EPS_BN);
  }
}

// ---------------- BN apply (+ residual), write h fp32 and h bf16 ----------------
__global__ void se_bn(const float* __restrict__ y, const float* __restrict__ musig,
                      const float* __restrict__ gamma, const float* __restrict__ beta,
                      float* __restrict__ h, ushort* __restrict__ h_bf, int residual) {
  int idx = blockIdx.x * 256 + threadIdx.x;     // [0, N*32) float4 units
  if (idx >= N_NODES * 32) return;
  int q = idx & 31;
  float4 yv = ((const float4*)y)[idx];
  float4 mu = ((const float4*)musig)[q];
  float4 rs = ((const float4*)(musig + 128))[q];
  float4 g  = ((const float4*)gamma)[q];
  float4 be = ((const float4*)beta)[q];
  float4 v;
  v.x = g.x * (yv.x - mu.x) * rs.x + be.x;
  v.y = g.y * (yv.y - mu.y) * rs.y + be.y;
  v.z = g.z * (yv.z - mu.z) * rs.z + be.z;
  v.w = g.w * (yv.w - mu.w) * rs.w + be.w;
  if (residual) {
    float4 hp = ((const float4*)h)[idx];
    v.x += hp.x; v.y += hp.y; v.z += hp.z; v.w += hp.w;
  }
  ((float4*)h)[idx] = v;
  ushort4 o;
  o.x = f2bf(v.x); o.y = f2bf(v.y); o.z = f2bf(v.z); o.w = f2bf(v.w);
  ((ushort4*)h_bf)[idx] = o;
}

// ---------------- mean pool by (sorted) batch ----------------
__global__ __launch_bounds__(256) void se_pool(const float* __restrict__ h,
                                               const int* __restrict__ batch, float* __restrict__ pool) {
  __shared__ float ps[NGRAPH * HID];
  __shared__ float pc[NGRAPH];
  const int tid = threadIdx.x, w = tid >> 6, l = tid & 63;
  for (int i = tid; i < NGRAPH * HID; i += 256) ps[i] = 0.f;
  if (tid < NGRAPH) pc[tid] = 0.f;
  __syncthreads();
  const int chunk = (N_NODES + gridDim.x - 1) / gridDim.x;
  const int start = blockIdx.x * chunk;
  const int end = min(N_NODES, start + chunk);
  for (int n = start + w; n < end; n += 4) {
    const int g = batch[n];
    const float2 v = ((const float2*)h)[n * 64 + l];
    unsafeAtomicAdd(&ps[g * HID + 2 * l], v.x);
    unsafeAtomicAdd(&ps[g * HID + 2 * l + 1], v.y);
    if (l == 0) unsafeAtomicAdd(&pc[g], 1.f);
  }
  __syncthreads();
  for (int i = tid; i < NGRAPH * HID; i += 256) {
    const float v = ps[i];
    if (v != 0.f) unsafeAtomicAdd(&pool[i], v);
  }
  if (tid < NGRAPH) {
    const float v = pc[tid];
    if (v != 0.f) unsafeAtomicAdd(&pool[NGRAPH * HID + tid], v);
  }
}
__global__ void se_poolfin(const float* __restrict__ pool, float* __restrict__ out) {
  int idx = blockIdx.x * 256 + threadIdx.x;
  if (idx < NGRAPH * HID) {
    int g = idx >> 7;
    out[idx] = pool[idx] / fmaxf(pool[NGRAPH * HID + g], 1.f);
  }
}

extern "C" void kernel_launch(void* const* d_in, const int* in_sizes, int n_in,
                              void* d_out, int out_size, void* d_ws, size_t ws_size,
                              hipStream_t stream) {
  (void)in_sizes; (void)n_in; (void)out_size; (void)ws_size;
  const int*   tok_id  = (const int*)d_in[0];
  const float* bbox    = (const float*)d_in[1];
  const int*   ei      = (const int*)d_in[2];
  const int*   eattr   = (const int*)d_in[3];
  const int*   batch   = (const int*)d_in[4];
  const float* tok_emb = (const float*)d_in[5];
  const float* bbox_W  = (const float*)d_in[6];
  const float* bbox_b  = (const float*)d_in[7];
  const float* rel_emb = (const float*)d_in[8];
  const float* Wl0  = (const float*)d_in[9];
  const float* bl0  = (const float*)d_in[10];
  const float* Wr0  = (const float*)d_in[11];
  const float* br0  = (const float*)d_in[12];
  const float* We0  = (const float*)d_in[13];
  const float* att0 = (const float*)d_in[14];
  const float* bias0  = (const float*)d_in[15];
  const float* gamma0 = (const float*)d_in[16];
  const float* beta0  = (const float*)d_in[17];
  const float* WlS  = (const float*)d_in[18];
  const float* blS  = (const float*)d_in[19];
  const float* WrS  = (const float*)d_in[20];
  const float* brS  = (const float*)d_in[21];
  const float* WeS  = (const float*)d_in[22];
  const float* attS = (const float*)d_in[23];
  const float* biasS  = (const float*)d_in[24];
  const float* gammaS = (const float*)d_in[25];
  const float* betaS  = (const float*)d_in[26];
  float* out = (float*)d_out;

  char* ws = (char*)d_ws;
  size_t off = 0;
  auto alloc = [&](size_t bytes) -> char* {
    char* p = ws + off;
    off = (off + bytes + 255) & ~(size_t)255;
    return p;
  };
  ushort* x_bf = (ushort*)alloc((size_t)N_PAD * IN0 * 2);  // 57.7MB; reused as y (51.2MB)
  float*  y    = (float*)x_bf;
  ushort* xlxr = (ushort*)alloc((size_t)N_PAD * 256 * 2);
  float*  h    = (float*)alloc((size_t)N_NODES * HID * 4);
  ushort* h_bf = (ushort*)alloc((size_t)N_PAD * HID * 2);
  ushort* W0T  = (ushort*)alloc((size_t)256 * IN0 * 2);
  ushort* WST  = (ushort*)alloc((size_t)2 * 256 * HID * 2);
  float*  eetab   = (float*)alloc((size_t)3 * NREL * HID * 4);
  float*  biascat = (float*)alloc((size_t)3 * 256 * 4);
  int* deg  = (int*)alloc((size_t)N_NODES * 4);
  int* offs = (int*)alloc((size_t)(N_NODES + 1) * 4);
  int* cur  = (int*)alloc((size_t)N_NODES * 4);
  int* bsum = (int*)alloc(128 * 4);
  int2* csr = (int2*)alloc((size_t)N_EDGES * 8);
  float* partial = (float*)alloc((size_t)256 * AGG_BLOCKS * 4);
  float* musig   = (float*)alloc(256 * 4);
  float* pool    = (float*)alloc((size_t)(NGRAPH * HID + NGRAPH) * 4);

  hipMemsetAsync(deg, 0, (size_t)N_NODES * 4, stream);
  hipMemsetAsync(cur, 0, (size_t)N_NODES * 4, stream);
  hipMemsetAsync(pool, 0, (size_t)(NGRAPH * HID + NGRAPH) * 4, stream);

  se_prep<<<624, 256, 0, stream>>>(Wl0, Wr0, WlS, WrS, rel_emb, We0, WeS,
                                   bl0, br0, blS, brS, W0T, WST, eetab, biascat);
  se_build_x<<<(N_PAD * IN0 + 255) / 256, 256, 0, stream>>>(tok_id, bbox, tok_emb, bbox_W, bbox_b, x_bf);
  se_hist<<<(N_EDGES + 255) / 256, 256, 0, stream>>>(ei, deg);
  se_scanA<<<98, 1024, 0, stream>>>(deg, offs, bsum);
  se_scanB<<<1, 1, 0, stream>>>(bsum, 98);
  se_scanC<<<98, 1024, 0, stream>>>(offs, bsum);
  se_scatter<<<(N_EDGES + 255) / 256, 256, 0, stream>>>(ei, eattr, offs, cur, csr);

  // layer 0 (K=288)
  se_gemm<IN0><<<dim3(N_PAD / 128, 2), 256, 0, stream>>>(x_bf, W0T, biascat, xlxr);
  se_agg<<<AGG_BLOCKS, 256, 0, stream>>>((const uint*)xlxr, csr, offs, deg,
                                         eetab, att0, bias0, y, partial);
  se_stats<<<128, 256, 0, stream>>>(partial, musig);
  se_bn<<<(N_NODES * 32 + 255) / 256, 256, 0, stream>>>(y, musig, gamma0, beta0, h, h_bf, 0);

  // layers 1..2 (K=128)
  for (int li = 0; li < 2; ++li) {
    se_gemm<HID><<<dim3(N_PAD / 128, 2), 256, 0, stream>>>(h_bf, WST + (size_t)li * 256 * HID,
                                                           biascat + (li + 1) * 256, xlxr);
    se_agg<<<AGG_BLOCKS, 256, 0, stream>>>((const uint*)xlxr, csr, offs, deg,
                                           eetab + (size_t)(li + 1) * NREL * HID,
                                           attS + (size_t)li * NHEAD * NCH,
                                           biasS + (size_t)li * HID, y, partial);
    se_stats<<<128, 256, 0, stream>>>(partial, musig);
    se_bn<<<(N_NODES * 32 + 255) / 256, 256, 0, stream>>>(y, musig, gammaS + (size_t)li * HID,
                                                          betaS + (size_t)li * HID, h, h_bf, 1);
  }

  se_pool<<<POOL_BLOCKS, 256, 0, stream>>>(h, batch, pool);
  se_poolfin<<<32, 256, 0, stream>>>(pool, out);
}

// Round 2
// 1027.949 us; speedup vs baseline: 1.3354x; 1.3354x over previous
//
#include <hip/hip_runtime.h>

#define N_NODES 100000
#define N_PAD   100096
#define N_EDGES 1600000
#define NGRAPH  64
#define NHEAD   8
#define NCH     16
#define HID     128
#define IN0     288
#define NREL    51
#define EMB     256
#define NBBOX   32
#define NEG_SLOPE 0.2f
#define EPS_BN  1e-5f
#define AGG_BLOCKS 1536
#define POOL_BLOCKS 128

typedef unsigned int uint;
typedef unsigned short ushort;

typedef __bf16 bf16_t;
typedef bf16_t bfx8 __attribute__((ext_vector_type(8)));
typedef float  fx4  __attribute__((ext_vector_type(4)));

__device__ __forceinline__ ushort f2bf(float f) {
  uint u = __float_as_uint(f);
  u += 0x7fffu + ((u >> 16) & 1u);
  return (ushort)(u >> 16);
}
__device__ __forceinline__ float bf2f(uint u) { return __uint_as_float(u << 16); }
__device__ __forceinline__ void unpack8(uint4 u, float* f) {
  f[0] = __uint_as_float(u.x << 16); f[1] = __uint_as_float(u.x & 0xffff0000u);
  f[2] = __uint_as_float(u.y << 16); f[3] = __uint_as_float(u.y & 0xffff0000u);
  f[4] = __uint_as_float(u.z << 16); f[5] = __uint_as_float(u.z & 0xffff0000u);
  f[6] = __uint_as_float(u.w << 16); f[7] = __uint_as_float(u.w & 0xffff0000u);
}

// ---------------- prep: weight transpose->bf16, ee tables, bias concat ----------------
__global__ void se_prep(const float* __restrict__ Wl0, const float* __restrict__ Wr0,
                        const float* __restrict__ WlS, const float* __restrict__ WrS,
                        const float* __restrict__ rel_emb, const float* __restrict__ We0,
                        const float* __restrict__ WeS,
                        const float* __restrict__ bl0, const float* __restrict__ br0,
                        const float* __restrict__ blS, const float* __restrict__ brS,
                        ushort* __restrict__ W0T, ushort* __restrict__ WST,
                        float* __restrict__ eetab, float* __restrict__ biascat) {
  int i = blockIdx.x * 256 + threadIdx.x;
  if (i < 256 * IN0) {                       // W0T[j][k] = Wl0|Wr0 [k][j]
    int j = i / IN0, k = i - j * IN0;
    float v = (j < 128) ? Wl0[k * 128 + j] : Wr0[k * 128 + (j - 128)];
    W0T[j * IN0 + k] = f2bf(v);
    return;
  }
  i -= 256 * IN0;
  if (i < 2 * 256 * HID) {                   // WST[l][j][k]
    int li = i >> 15;
    int rem = i & 32767;
    int j = rem >> 7, k = rem & 127;
    float v = (j < 128) ? WlS[(li * 128 + k) * 128 + j] : WrS[(li * 128 + k) * 128 + (j - 128)];
    WST[(li * 256 + j) * 128 + k] = f2bf(v);
    return;
  }
  i -= 2 * 256 * HID;
  if (i < 3 * NREL * HID) {                  // eetab[l][r][j] = sum_c rel[r][c]*We_l[c][j]
    int li = i / (NREL * HID);
    int rem = i - li * (NREL * HID);
    int r = rem >> 7, j = rem & 127;
    const float* We = (li == 0) ? We0 : (WeS + (li - 1) * NCH * HID);
    float s = 0.f;
#pragma unroll
    for (int c = 0; c < NCH; c++) s += rel_emb[r * NCH + c] * We[c * HID + j];
    eetab[li * (NREL * HID) + rem] = s;
    return;
  }
  i -= 3 * NREL * HID;
  if (i < 3 * 256) {                         // biascat[l][256] = bl|br
    int li = i >> 8, j = i & 255;
    const float* bl = (li == 0) ? bl0 : (blS + (li - 1) * HID);
    const float* br = (li == 0) ? br0 : (brS + (li - 1) * HID);
    biascat[i] = (j < 128) ? bl[j] : br[j - 128];
  }
}

// ---------------- build x = [tok_emb[tok] | bbox@W+b] as bf16 (8ch/thread), zero-pad rows ----------------
__global__ void se_build_x(const int* __restrict__ tok_id, const float* __restrict__ bbox,
                           const float* __restrict__ tok_emb, const float* __restrict__ bbox_W,
                           const float* __restrict__ bbox_b, ushort* __restrict__ x) {
  int idx = blockIdx.x * 256 + threadIdx.x;   // one uint4 = 8 channels
  if (idx >= N_PAD * 36) return;
  int n = idx / 36, c = (idx - n * 36) * 8;
  float f[8];
  if (n >= N_NODES) {
#pragma unroll
    for (int j = 0; j < 8; j++) f[j] = 0.f;
  } else if (c < EMB) {
    const float* te = tok_emb + (size_t)tok_id[n] * EMB + c;
    const float4 t0 = *(const float4*)te, t1 = *(const float4*)(te + 4);
    f[0] = t0.x; f[1] = t0.y; f[2] = t0.z; f[3] = t0.w;
    f[4] = t1.x; f[5] = t1.y; f[6] = t1.z; f[7] = t1.w;
  } else {
    const int j0 = c - EMB;
    const float4 bb = *(const float4*)(bbox + (size_t)n * 4);
#pragma unroll
    for (int j = 0; j < 8; j++) {
      float v = bbox_b[j0 + j];
      v += bb.x * bbox_W[0 * NBBOX + j0 + j];
      v += bb.y * bbox_W[1 * NBBOX + j0 + j];
      v += bb.z * bbox_W[2 * NBBOX + j0 + j];
      v += bb.w * bbox_W[3 * NBBOX + j0 + j];
      f[j] = v;
    }
  }
  uint4 p;
  p.x = ((uint)f2bf(f[1]) << 16) | f2bf(f[0]);
  p.y = ((uint)f2bf(f[3]) << 16) | f2bf(f[2]);
  p.z = ((uint)f2bf(f[5]) << 16) | f2bf(f[4]);
  p.w = ((uint)f2bf(f[7]) << 16) | f2bf(f[6]);
  ((uint4*)x)[idx] = p;
}

// ---------------- CSR build ----------------
__global__ void se_hist(const int* __restrict__ ei, int* __restrict__ deg) {
  int e = blockIdx.x * 256 + threadIdx.x;
  if (e < N_EDGES) atomicAdd(&deg[ei[N_EDGES + e]], 1);
}
__global__ __launch_bounds__(1024) void se_scanA(const int* __restrict__ deg,
                                                 int* __restrict__ offs, int* __restrict__ bsum) {
  __shared__ int s[1024];
  const int tid = threadIdx.x;
  const int i = blockIdx.x * 1024 + tid;
  int v = (i < N_NODES) ? deg[i] : 0;
  s[tid] = v;
  __syncthreads();
  for (int d = 1; d < 1024; d <<= 1) {
    int t = (tid >= d) ? s[tid - d] : 0;
    __syncthreads();
    s[tid] += t;
    __syncthreads();
  }
  if (i < N_NODES) offs[i] = s[tid] - v;
  if (tid == 1023) bsum[blockIdx.x] = s[1023];
}
__global__ __launch_bounds__(128) void se_scanB(int* __restrict__ bsum, int nb) {
  __shared__ int s[128];
  const int t = threadIdx.x;
  int v = (t < nb) ? bsum[t] : 0;
  s[t] = v;
  __syncthreads();
  for (int d = 1; d < 128; d <<= 1) {
    int u = (t >= d) ? s[t - d] : 0;
    __syncthreads();
    s[t] += u;
    __syncthreads();
  }
  if (t < nb) bsum[t] = s[t] - v;   // exclusive
}
__global__ __launch_bounds__(1024) void se_scanC(int* __restrict__ offs, const int* __restrict__ bsum) {
  int i = blockIdx.x * 1024 + threadIdx.x;
  if (i < N_NODES) offs[i] += bsum[blockIdx.x];
}
__global__ void se_scatter(const int* __restrict__ ei, const int* __restrict__ eattr,
                           const int* __restrict__ offs, int* __restrict__ cur, int2* __restrict__ csr) {
  int e = blockIdx.x * 256 + threadIdx.x;
  if (e < N_EDGES) {
    int d = ei[N_EDGES + e];
    int p = offs[d] + atomicAdd(&cur[d], 1);
    csr[p] = make_int2(ei[e], eattr[e]);
  }
}

// ---------------- GEMM: C[N,256] = A[N,K] @ BT[256,K]^T + biascat, bf16 in/out, fp32 acc ----------------
template <int K>
__global__ __launch_bounds__(256) void se_gemm(const ushort* __restrict__ A,
                                               const ushort* __restrict__ BT,
                                               const float* __restrict__ bias,
                                               ushort* __restrict__ C) {
  __shared__ __align__(16) ushort As[128 * 32];
  __shared__ __align__(16) ushort Bs[128 * 32];
  const int tid = threadIdx.x;
  const int w = tid >> 6, l = tid & 63;
  const int wr = w >> 1, wc = w & 1;
  const int m0 = blockIdx.x * 128, n0 = blockIdx.y * 128;
  fx4 acc[4][4];
#pragma unroll
  for (int i = 0; i < 4; i++)
#pragma unroll
    for (int j = 0; j < 4; j++) acc[i][j] = fx4{0.f, 0.f, 0.f, 0.f};

  for (int k0 = 0; k0 < K; k0 += 32) {
#pragma unroll
    for (int ch = 0; ch < 2; ch++) {
      const int t = tid + ch * 256;          // 16B chunk id; row=t/4, col=(t%4)*8
      const int r = t >> 2, c = (t & 3) << 3;
      const ushort* ga = A + (size_t)(m0 + r) * K + (k0 + c);
      ushort* la = As + (size_t)(ch * 256 + w * 64) * 8;
      __builtin_amdgcn_global_load_lds((const __attribute__((address_space(1))) void*)ga,
                                       (__attribute__((address_space(3))) void*)la, 16, 0, 0);
      const ushort* gb = BT + (size_t)(n0 + r) * K + (k0 + c);
      ushort* lb = Bs + (size_t)(ch * 256 + w * 64) * 8;
      __builtin_amdgcn_global_load_lds((const __attribute__((address_space(1))) void*)gb,
                                       (__attribute__((address_space(3))) void*)lb, 16, 0, 0);
    }
    __syncthreads();
    bfx8 af[4], bfr[4];
#pragma unroll
    for (int i = 0; i < 4; i++) {
      af[i]  = *(const bfx8*)(As + ((wr * 64 + i * 16 + (l & 15)) * 32 + ((l >> 4) * 8)));
      bfr[i] = *(const bfx8*)(Bs + ((wc * 64 + i * 16 + (l & 15)) * 32 + ((l >> 4) * 8)));
    }
#pragma unroll
    for (int i = 0; i < 4; i++)
#pragma unroll
      for (int j = 0; j < 4; j++)
        acc[i][j] = __builtin_amdgcn_mfma_f32_16x16x32_bf16(af[i], bfr[j], acc[i][j], 0, 0, 0);
    __syncthreads();
  }
#pragma unroll
  for (int i = 0; i < 4; i++) {
    const int rbase = m0 + wr * 64 + i * 16 + ((l >> 4) << 2);
#pragma unroll
    for (int j = 0; j < 4; j++) {
      const int col = n0 + wc * 64 + j * 16 + (l & 15);
      const float bz = bias[col];
#pragma unroll
      for (int r2 = 0; r2 < 4; r2++) {
        const int row = rbase + r2;
        if (row < N_NODES) C[(size_t)row * 256 + col] = f2bf(acc[i][j][r2] + bz);
      }
    }
  }
}

// ---------------- GATv2 aggregation: 4 edges/wave (16 lanes each), online softmax ----------------
__global__ __launch_bounds__(256) void se_agg(const uint4* __restrict__ xlxr4,
                                              const int2* __restrict__ csr,
                                              const int* __restrict__ offs, const int* __restrict__ deg,
                                              const float* __restrict__ eetab,
                                              const float* __restrict__ att,
                                              const float* __restrict__ bias,
                                              ushort* __restrict__ y, float* __restrict__ partial) {
  __shared__ ushort ee[NREL * HID];       // bf16 edge tables, 13056 B
  __shared__ float bstat[256];
  const int tid = threadIdx.x, w = tid >> 6, l = tid & 63;
  const int g = l >> 4, k = l & 15;       // group (edge slot), lane-in-group (8 channels)
  for (int i = tid; i < NREL * HID; i += 256) ee[i] = f2bf(eetab[i]);
  bstat[tid] = 0.f;
  __syncthreads();
  // per-lane constants for channels k*8 .. k*8+7 (head = k>>1)
  float attv[8], biasv[8];
  {
    const float* ap = att + (k >> 1) * NCH + (k & 1) * 8;
    const float* bp = bias + k * 8;
#pragma unroll
    for (int j = 0; j < 8; j++) { attv[j] = ap[j]; biasv[j] = bp[j]; }
  }
  float sreg[8], qreg[8];
#pragma unroll
  for (int j = 0; j < 8; j++) { sreg[j] = 0.f; qreg[j] = 0.f; }

  const int stride = gridDim.x * 4;
  for (int n = blockIdx.x * 4 + w; n < N_NODES; n += stride) {
    const int rs = offs[n], dg = deg[n];
    float xr[8];
    {
      const uint4 xru = xlxr4[(size_t)n * 32 + 16 + k];
      unpack8(xru, xr);
    }
    float mx = -1e30f, den = 0.f;
    float acc[8];
#pragma unroll
    for (int j = 0; j < 8; j++) acc[j] = 0.f;

    if (dg > 0) {
      int2 eA = make_int2(0, 0), eB = make_int2(0, 0);
      uint4 xlv = uint4{0u, 0u, 0u, 0u};
      if (g < dg) eA = csr[rs + g];
      if (g < dg) xlv = xlxr4[(size_t)eA.x * 32 + k];
      if (4 + g < dg) eB = csr[rs + 4 + g];
      const int nit = (dg + 3) >> 2;
      for (int i = 0; i < nit; ++i) {
        const int2 ec = eA;
        const uint4 xc = xlv;
        const bool vc = (4 * i + g) < dg;
        eA = eB;
        if (4 * (i + 1) + g < dg) xlv = xlxr4[(size_t)eA.x * 32 + k];   // gather for i+1
        if (4 * (i + 2) + g < dg) eB = csr[rs + 4 * (i + 2) + g];       // csr for i+2
        const uint4 eeu = *(const uint4*)(ee + ec.y * HID + k * 8);
        float xl[8], eef[8];
        unpack8(xc, xl);
        unpack8(eeu, eef);
        float sdot = 0.f;
#pragma unroll
        for (int j = 0; j < 8; j++) {
          float m = xl[j] + xr[j] + eef[j];
          m = fmaxf(m, 0.f) + NEG_SLOPE * fminf(m, 0.f);
          sdot = fmaf(m, attv[j], sdot);
        }
        sdot += __shfl_xor(sdot, 1);        // 16-channel head dot across lane pair
        const float s = vc ? sdot : -1e30f;
        const float mn = fmaxf(mx, s);
        const float scl = __expf(mx - mn);
        const float p = __expf(s - mn);
        den = den * scl + p;
#pragma unroll
        for (int j = 0; j < 8; j++) acc[j] = fmaf(acc[j], scl, p * xl[j]);
        mx = mn;
      }
      // combine 4 edge-groups (lanes xor 16, 32)
#pragma unroll
      for (int lvl = 16; lvl <= 32; lvl <<= 1) {
        const float mo = __shfl_xor(mx, lvl);
        const float dno = __shfl_xor(den, lvl);
        float aco[8];
#pragma unroll
        for (int j = 0; j < 8; j++) aco[j] = __shfl_xor(acc[j], lvl);
        const float mn = fmaxf(mx, mo);
        const float sa = __expf(mx - mn), sb = __expf(mo - mn);
        den = den * sa + dno * sb;
#pragma unroll
        for (int j = 0; j < 8; j++) acc[j] = acc[j] * sa + aco[j] * sb;
        mx = mn;
      }
    }
    const float r = 1.f / fmaxf(den, 1e-16f);
    float o[8];
#pragma unroll
    for (int j = 0; j < 8; j++) {
      o[j] = fmaxf(fmaf(acc[j], r, biasv[j]), 0.f);
      sreg[j] += o[j];
      qreg[j] = fmaf(o[j], o[j], qreg[j]);
    }
    if (g == 0) {
      uint4 p4;
      p4.x = ((uint)f2bf(o[1]) << 16) | f2bf(o[0]);
      p4.y = ((uint)f2bf(o[3]) << 16) | f2bf(o[2]);
      p4.z = ((uint)f2bf(o[5]) << 16) | f2bf(o[4]);
      p4.w = ((uint)f2bf(o[7]) << 16) | f2bf(o[6]);
      ((uint4*)y)[(size_t)n * 16 + k] = p4;
    }
  }
  if (l < 16) {
#pragma unroll
    for (int j = 0; j < 8; j++) {
      unsafeAtomicAdd(&bstat[k * 8 + j], sreg[j]);
      unsafeAtomicAdd(&bstat[128 + k * 8 + j], qreg[j]);
    }
  }
  __syncthreads();
  partial[(size_t)tid * AGG_BLOCKS + blockIdx.x] = bstat[tid];
}

// ---------------- BN stats finalize: mean + rsqrt(var+eps) per channel ----------------
__global__ __launch_bounds__(256) void se_stats(const float* __restrict__ partial, float* __restrict__ musig) {
  __shared__ float red[256];
  const int ch = blockIdx.x, tid = threadIdx.x;
  float s = 0.f;
  for (int i = tid; i < AGG_BLOCKS; i += 256) s += partial[ch * AGG_BLOCKS + i];
  red[tid] = s; __syncthreads();
  for (int o = 128; o > 0; o >>= 1) { if (tid < o) red[tid] += red[tid + o]; __syncthreads(); }
  const float sum = red[0]; __syncthreads();
  float q = 0.f;
  for (int i = tid; i < AGG_BLOCKS; i += 256) q += partial[(128 + ch) * AGG_BLOCKS + i];
  red[tid] = q; __syncthreads();
  for (int o = 128; o > 0; o >>= 1) { if (tid < o) red[tid] += red[tid + o]; __syncthreads(); }
  if (tid == 0) {
    const float mean = sum / (float)N_NODES;
    const float var = red[0] / (float)N_NODES - mean * mean;
    musig[ch] = mean;
    musig[128 + ch] = rsqrtf(var + EPS_BN);
  }
}

// ---------------- BN apply (+ residual), y bf16 in; write h fp32 and h bf16 ----------------
__global__ void se_bn(const ushort* __restrict__ y, const float* __restrict__ musig,
                      const float* __restrict__ gamma, const float* __restrict__ beta,
                      float* __restrict__ h, ushort* __restrict__ h_bf, int residual) {
  int idx = blockIdx.x * 256 + threadIdx.x;     // one uint4 = 8 channels
  if (idx >= N_NODES * 16) return;
  const int k = idx & 15;                       // ch = k*8
  const uint4 yv = ((const uint4*)y)[idx];
  float f[8];
  unpack8(yv, f);
  const float4 mu0 = ((const float4*)musig)[k * 2],         mu1 = ((const float4*)musig)[k * 2 + 1];
  const float4 rs0 = ((const float4*)(musig + 128))[k * 2], rs1 = ((const float4*)(musig + 128))[k * 2 + 1];
  const float4 g0  = ((const float4*)gamma)[k * 2],         g1  = ((const float4*)gamma)[k * 2 + 1];
  const float4 b0  = ((const float4*)beta)[k * 2],          b1  = ((const float4*)beta)[k * 2 + 1];
  float v[8];
  v[0] = g0.x * (f[0] - mu0.x) * rs0.x + b0.x;
  v[1] = g0.y * (f[1] - mu0.y) * rs0.y + b0.y;
  v[2] = g0.z * (f[2] - mu0.z) * rs0.z + b0.z;
  v[3] = g0.w * (f[3] - mu0.w) * rs0.w + b0.w;
  v[4] = g1.x * (f[4] - mu1.x) * rs1.x + b1.x;
  v[5] = g1.y * (f[5] - mu1.y) * rs1.y + b1.y;
  v[6] = g1.z * (f[6] - mu1.z) * rs1.z + b1.z;
  v[7] = g1.w * (f[7] - mu1.w) * rs1.w + b1.w;
  float4* hp = (float4*)h + (size_t)idx * 2;
  if (residual) {
    const float4 h0 = hp[0], h1 = hp[1];
    v[0] += h0.x; v[1] += h0.y; v[2] += h0.z; v[3] += h0.w;
    v[4] += h1.x; v[5] += h1.y; v[6] += h1.z; v[7] += h1.w;
  }
  hp[0] = make_float4(v[0], v[1], v[2], v[3]);
  hp[1] = make_float4(v[4], v[5], v[6], v[7]);
  uint4 p4;
  p4.x = ((uint)f2bf(v[1]) << 16) | f2bf(v[0]);
  p4.y = ((uint)f2bf(v[3]) << 16) | f2bf(v[2]);
  p4.z = ((uint)f2bf(v[5]) << 16) | f2bf(v[4]);
  p4.w = ((uint)f2bf(v[7]) << 16) | f2bf(v[6]);
  ((uint4*)h_bf)[idx] = p4;
}

// ---------------- mean pool by (sorted) batch ----------------
__global__ __launch_bounds__(256) void se_pool(const float* __restrict__ h,
                                               const int* __restrict__ batch, float* __restrict__ pool) {
  __shared__ float ps[NGRAPH * HID];
  __shared__ float pc[NGRAPH];
  const int tid = threadIdx.x, w = tid >> 6, l = tid & 63;
  for (int i = tid; i < NGRAPH * HID; i += 256) ps[i] = 0.f;
  if (tid < NGRAPH) pc[tid] = 0.f;
  __syncthreads();
  const int chunk = (N_NODES + gridDim.x - 1) / gridDim.x;
  const int start = blockIdx.x * chunk;
  const int end = min(N_NODES, start + chunk);
  for (int n = start + w; n < end; n += 4) {
    const int g = batch[n];
    const float2 v = ((const float2*)h)[n * 64 + l];
    unsafeAtomicAdd(&ps[g * HID + 2 * l], v.x);
    unsafeAtomicAdd(&ps[g * HID + 2 * l + 1], v.y);
    if (l == 0) unsafeAtomicAdd(&pc[g], 1.f);
  }
  __syncthreads();
  for (int i = tid; i < NGRAPH * HID; i += 256) {
    const float v = ps[i];
    if (v != 0.f) unsafeAtomicAdd(&pool[i], v);
  }
  if (tid < NGRAPH) {
    const float v = pc[tid];
    if (v != 0.f) unsafeAtomicAdd(&pool[NGRAPH * HID + tid], v);
  }
}
__global__ void se_poolfin(const float* __restrict__ pool, float* __restrict__ out) {
  int idx = blockIdx.x * 256 + threadIdx.x;
  if (idx < NGRAPH * HID) {
    int g = idx >> 7;
    out[idx] = pool[idx] / fmaxf(pool[NGRAPH * HID + g], 1.f);
  }
}

extern "C" void kernel_launch(void* const* d_in, const int* in_sizes, int n_in,
                              void* d_out, int out_size, void* d_ws, size_t ws_size,
                              hipStream_t stream) {
  (void)in_sizes; (void)n_in; (void)out_size; (void)ws_size;
  const int*   tok_id  = (const int*)d_in[0];
  const float* bbox    = (const float*)d_in[1];
  const int*   ei      = (const int*)d_in[2];
  const int*   eattr   = (const int*)d_in[3];
  const int*   batch   = (const int*)d_in[4];
  const float* tok_emb = (const float*)d_in[5];
  const float* bbox_W  = (const float*)d_in[6];
  const float* bbox_b  = (const float*)d_in[7];
  const float* rel_emb = (const float*)d_in[8];
  const float* Wl0  = (const float*)d_in[9];
  const float* bl0  = (const float*)d_in[10];
  const float* Wr0  = (const float*)d_in[11];
  const float* br0  = (const float*)d_in[12];
  const float* We0  = (const float*)d_in[13];
  const float* att0 = (const float*)d_in[14];
  const float* bias0  = (const float*)d_in[15];
  const float* gamma0 = (const float*)d_in[16];
  const float* beta0  = (const float*)d_in[17];
  const float* WlS  = (const float*)d_in[18];
  const float* blS  = (const float*)d_in[19];
  const float* WrS  = (const float*)d_in[20];
  const float* brS  = (const float*)d_in[21];
  const float* WeS  = (const float*)d_in[22];
  const float* attS = (const float*)d_in[23];
  const float* biasS  = (const float*)d_in[24];
  const float* gammaS = (const float*)d_in[25];
  const float* betaS  = (const float*)d_in[26];
  float* out = (float*)d_out;

  char* ws = (char*)d_ws;
  size_t off = 0;
  auto alloc = [&](size_t bytes) -> char* {
    char* p = ws + off;
    off = (off + bytes + 255) & ~(size_t)255;
    return p;
  };
  ushort* x_bf = (ushort*)alloc((size_t)N_PAD * IN0 * 2);  // 57.7MB; reused as y (bf16, 25.6MB)
  ushort* y    = x_bf;
  ushort* xlxr = (ushort*)alloc((size_t)N_PAD * 256 * 2);
  float*  h    = (float*)alloc((size_t)N_NODES * HID * 4);
  ushort* h_bf = (ushort*)alloc((size_t)N_PAD * HID * 2);
  ushort* W0T  = (ushort*)alloc((size_t)256 * IN0 * 2);
  ushort* WST  = (ushort*)alloc((size_t)2 * 256 * HID * 2);
  float*  eetab   = (float*)alloc((size_t)3 * NREL * HID * 4);
  float*  biascat = (float*)alloc((size_t)3 * 256 * 4);
  int* deg  = (int*)alloc((size_t)N_NODES * 4);
  int* offs = (int*)alloc((size_t)(N_NODES + 1) * 4);
  int* cur  = (int*)alloc((size_t)N_NODES * 4);
  int* bsum = (int*)alloc(128 * 4);
  int2* csr = (int2*)alloc((size_t)N_EDGES * 8);
  float* partial = (float*)alloc((size_t)256 * AGG_BLOCKS * 4);
  float* musig   = (float*)alloc(256 * 4);
  float* pool    = (float*)alloc((size_t)(NGRAPH * HID + NGRAPH) * 4);

  hipMemsetAsync(deg, 0, (size_t)N_NODES * 4, stream);
  hipMemsetAsync(cur, 0, (size_t)N_NODES * 4, stream);
  hipMemsetAsync(pool, 0, (size_t)(NGRAPH * HID + NGRAPH) * 4, stream);

  se_prep<<<624, 256, 0, stream>>>(Wl0, Wr0, WlS, WrS, rel_emb, We0, WeS,
                                   bl0, br0, blS, brS, W0T, WST, eetab, biascat);
  se_build_x<<<(N_PAD * 36 + 255) / 256, 256, 0, stream>>>(tok_id, bbox, tok_emb, bbox_W, bbox_b, x_bf);
  se_hist<<<(N_EDGES + 255) / 256, 256, 0, stream>>>(ei, deg);
  se_scanA<<<98, 1024, 0, stream>>>(deg, offs, bsum);
  se_scanB<<<1, 128, 0, stream>>>(bsum, 98);
  se_scanC<<<98, 1024, 0, stream>>>(offs, bsum);
  se_scatter<<<(N_EDGES + 255) / 256, 256, 0, stream>>>(ei, eattr, offs, cur, csr);

  // layer 0 (K=288)
  se_gemm<IN0><<<dim3(N_PAD / 128, 2), 256, 0, stream>>>(x_bf, W0T, biascat, xlxr);
  se_agg<<<AGG_BLOCKS, 256, 0, stream>>>((const uint4*)xlxr, csr, offs, deg,
                                         eetab, att0, bias0, y, partial);
  se_stats<<<128, 256, 0, stream>>>(partial, musig);
  se_bn<<<(N_NODES * 16 + 255) / 256, 256, 0, stream>>>(y, musig, gamma0, beta0, h, h_bf, 0);

  // layers 1..2 (K=128)
  for (int li = 0; li < 2; ++li) {
    se_gemm<HID><<<dim3(N_PAD / 128, 2), 256, 0, stream>>>(h_bf, WST + (size_t)li * 256 * HID,
                                                           biascat + (li + 1) * 256, xlxr);
    se_agg<<<AGG_BLOCKS, 256, 0, stream>>>((const uint4*)xlxr, csr, offs, deg,
                                           eetab + (size_t)(li + 1) * NREL * HID,
                                           attS + (size_t)li * NHEAD * NCH,
                                           biasS + (size_t)li * HID, y, partial);
    se_stats<<<128, 256, 0, stream>>>(partial, musig);
    se_bn<<<(N_NODES * 16 + 255) / 256, 256, 0, stream>>>(y, musig, gammaS + (size_t)li * HID,
                                                          betaS + (size_t)li * HID, h, h_bf, 1);
  }

  se_pool<<<POOL_BLOCKS, 256, 0, stream>>>(h, batch, pool);
  se_poolfin<<<32, 256, 0, stream>>>(pool, out);
}

// Round 3
// 964.469 us; speedup vs baseline: 1.4233x; 1.0658x over previous
//
#include <hip/hip_runtime.h>

#define N_NODES 100000
#define N_PAD   100096
#define N_EDGES 1600000
#define NGRAPH  64
#define NHEAD   8
#define NCH     16
#define HID     128
#define IN0     288
#define NREL    51
#define EMB     256
#define NBBOX   32
#define NEG_SLOPE 0.2f
#define EPS_BN  1e-5f
#define AGG_BLOCKS 2048
#define POOL_BLOCKS 128
#define SENT 0x03F00000u          /* rel=63, src=0 */
#define SENT_MIN ((uint)(NREL) << 20)
#define L2E 1.4426950408889634f

typedef unsigned int uint;
typedef unsigned short ushort;

typedef __bf16 bf16_t;
typedef bf16_t bfx8 __attribute__((ext_vector_type(8)));
typedef float  fx4  __attribute__((ext_vector_type(4)));
typedef float  v2f  __attribute__((ext_vector_type(2)));

__device__ __forceinline__ ushort f2bf(float f) {
  uint u = __float_as_uint(f);
  u += 0x7fffu + ((u >> 16) & 1u);
  return (ushort)(u >> 16);
}
__device__ __forceinline__ float bf2f(uint u) { return __uint_as_float(u << 16); }
__device__ __forceinline__ v2f up2(uint u) {
  v2f r;
  r.x = __uint_as_float(u << 16);
  r.y = __uint_as_float(u & 0xffff0000u);
  return r;
}
__device__ __forceinline__ void unpack8(uint4 u, float* f) {
  f[0] = __uint_as_float(u.x << 16); f[1] = __uint_as_float(u.x & 0xffff0000u);
  f[2] = __uint_as_float(u.y << 16); f[3] = __uint_as_float(u.y & 0xffff0000u);
  f[4] = __uint_as_float(u.z << 16); f[5] = __uint_as_float(u.z & 0xffff0000u);
  f[6] = __uint_as_float(u.w << 16); f[7] = __uint_as_float(u.w & 0xffff0000u);
}

// ---------------- prep: weight transpose->bf16, ee tables, bias concat ----------------
__global__ void se_prep(const float* __restrict__ Wl0, const float* __restrict__ Wr0,
                        const float* __restrict__ WlS, const float* __restrict__ WrS,
                        const float* __restrict__ rel_emb, const float* __restrict__ We0,
                        const float* __restrict__ WeS,
                        const float* __restrict__ bl0, const float* __restrict__ br0,
                        const float* __restrict__ blS, const float* __restrict__ brS,
                        ushort* __restrict__ W0T, ushort* __restrict__ WST,
                        float* __restrict__ eetab, float* __restrict__ biascat) {
  int i = blockIdx.x * 256 + threadIdx.x;
  if (i < 256 * IN0) {                       // W0T[j][k] = Wl0|Wr0 [k][j]
    int j = i / IN0, k = i - j * IN0;
    float v = (j < 128) ? Wl0[k * 128 + j] : Wr0[k * 128 + (j - 128)];
    W0T[j * IN0 + k] = f2bf(v);
    return;
  }
  i -= 256 * IN0;
  if (i < 2 * 256 * HID) {                   // WST[l][j][k]
    int li = i >> 15;
    int rem = i & 32767;
    int j = rem >> 7, k = rem & 127;
    float v = (j < 128) ? WlS[(li * 128 + k) * 128 + j] : WrS[(li * 128 + k) * 128 + (j - 128)];
    WST[(li * 256 + j) * 128 + k] = f2bf(v);
    return;
  }
  i -= 2 * 256 * HID;
  if (i < 3 * NREL * HID) {                  // eetab[l][r][j] = sum_c rel[r][c]*We_l[c][j]
    int li = i / (NREL * HID);
    int rem = i - li * (NREL * HID);
    int r = rem >> 7, j = rem & 127;
    const float* We = (li == 0) ? We0 : (WeS + (li - 1) * NCH * HID);
    float s = 0.f;
#pragma unroll
    for (int c = 0; c < NCH; c++) s += rel_emb[r * NCH + c] * We[c * HID + j];
    eetab[li * (NREL * HID) + rem] = s;
    return;
  }
  i -= 3 * NREL * HID;
  if (i < 3 * 256) {                         // biascat[l][256] = bl|br
    int li = i >> 8, j = i & 255;
    const float* bl = (li == 0) ? bl0 : (blS + (li - 1) * HID);
    const float* br = (li == 0) ? br0 : (brS + (li - 1) * HID);
    biascat[i] = (j < 128) ? bl[j] : br[j - 128];
  }
}

// ---------------- build x = [tok_emb[tok] | bbox@W+b] as bf16 (8ch/thread), zero-pad rows ----------------
__global__ void se_build_x(const int* __restrict__ tok_id, const float* __restrict__ bbox,
                           const float* __restrict__ tok_emb, const float* __restrict__ bbox_W,
                           const float* __restrict__ bbox_b, ushort* __restrict__ x) {
  int idx = blockIdx.x * 256 + threadIdx.x;   // one uint4 = 8 channels
  if (idx >= N_PAD * 36) return;
  int n = idx / 36, c = (idx - n * 36) * 8;
  float f[8];
  if (n >= N_NODES) {
#pragma unroll
    for (int j = 0; j < 8; j++) f[j] = 0.f;
  } else if (c < EMB) {
    const float* te = tok_emb + (size_t)tok_id[n] * EMB + c;
    const float4 t0 = *(const float4*)te, t1 = *(const float4*)(te + 4);
    f[0] = t0.x; f[1] = t0.y; f[2] = t0.z; f[3] = t0.w;
    f[4] = t1.x; f[5] = t1.y; f[6] = t1.z; f[7] = t1.w;
  } else {
    const int j0 = c - EMB;
    const float4 bb = *(const float4*)(bbox + (size_t)n * 4);
#pragma unroll
    for (int j = 0; j < 8; j++) {
      float v = bbox_b[j0 + j];
      v += bb.x * bbox_W[0 * NBBOX + j0 + j];
      v += bb.y * bbox_W[1 * NBBOX + j0 + j];
      v += bb.z * bbox_W[2 * NBBOX + j0 + j];
      v += bb.w * bbox_W[3 * NBBOX + j0 + j];
      f[j] = v;
    }
  }
  uint4 p;
  p.x = ((uint)f2bf(f[1]) << 16) | f2bf(f[0]);
  p.y = ((uint)f2bf(f[3]) << 16) | f2bf(f[2]);
  p.z = ((uint)f2bf(f[5]) << 16) | f2bf(f[4]);
  p.w = ((uint)f2bf(f[7]) << 16) | f2bf(f[6]);
  ((uint4*)x)[idx] = p;
}

// ---------------- CSR build (rows padded to multiples of 4, sentinel-filled) ----------------
__global__ void se_hist(const int* __restrict__ ei, int* __restrict__ deg) {
  int e = blockIdx.x * 256 + threadIdx.x;
  if (e < N_EDGES) atomicAdd(&deg[ei[N_EDGES + e]], 1);
}
__global__ __launch_bounds__(1024) void se_scanA(const int* __restrict__ deg,
                                                 int* __restrict__ offs, int* __restrict__ bsum) {
  __shared__ int s[1024];
  const int tid = threadIdx.x;
  const int i = blockIdx.x * 1024 + tid;
  int v = (i < N_NODES) ? ((deg[i] + 3) & ~3) : 0;   // padded degree
  s[tid] = v;
  __syncthreads();
  for (int d = 1; d < 1024; d <<= 1) {
    int t = (tid >= d) ? s[tid - d] : 0;
    __syncthreads();
    s[tid] += t;
    __syncthreads();
  }
  if (i < N_NODES) offs[i] = s[tid] - v;
  if (tid == 1023) bsum[blockIdx.x] = s[1023];
}
__global__ __launch_bounds__(128) void se_scanB(int* __restrict__ bsum, int nb) {
  __shared__ int s[128];
  const int t = threadIdx.x;
  int v = (t < nb) ? bsum[t] : 0;
  s[t] = v;
  __syncthreads();
  for (int d = 1; d < 128; d <<= 1) {
    int u = (t >= d) ? s[t - d] : 0;
    __syncthreads();
    s[t] += u;
    __syncthreads();
  }
  if (t < nb) bsum[t] = s[t] - v;   // exclusive
}
__global__ __launch_bounds__(1024) void se_scanC(int* __restrict__ offs, const int* __restrict__ bsum) {
  int i = blockIdx.x * 1024 + threadIdx.x;
  if (i < N_NODES) offs[i] += bsum[blockIdx.x];
}
__global__ void se_padfill(const int* __restrict__ deg, const int* __restrict__ offs,
                           uint* __restrict__ csrp) {
  int n = blockIdx.x * 256 + threadIdx.x;
  if (n >= N_NODES) return;
  const int d = deg[n];
  const int s = offs[n] + d;
  const int c = ((d + 3) & ~3) - d;
  for (int j = 0; j < c; j++) csrp[s + j] = SENT;
}
__global__ void se_scatter(const int* __restrict__ ei, const int* __restrict__ eattr,
                           const int* __restrict__ offs, int* __restrict__ cur,
                           uint* __restrict__ csrp) {
  int e = blockIdx.x * 256 + threadIdx.x;
  if (e < N_EDGES) {
    int d = ei[N_EDGES + e];
    int p = offs[d] + atomicAdd(&cur[d], 1);
    csrp[p] = (uint)ei[e] | ((uint)eattr[e] << 20);
  }
}

// ---------------- GEMM: C[N,256] = A[N,K] @ BT[256,K]^T + biascat, bf16 in/out, fp32 acc ----------------
template <int K>
__global__ __launch_bounds__(256) void se_gemm(const ushort* __restrict__ A,
                                               const ushort* __restrict__ BT,
                                               const float* __restrict__ bias,
                                               ushort* __restrict__ C) {
  __shared__ __align__(16) ushort As[128 * 32];
  __shared__ __align__(16) ushort Bs[128 * 32];
  const int tid = threadIdx.x;
  const int w = tid >> 6, l = tid & 63;
  const int wr = w >> 1, wc = w & 1;
  const int m0 = blockIdx.x * 128, n0 = blockIdx.y * 128;
  fx4 acc[4][4];
#pragma unroll
  for (int i = 0; i < 4; i++)
#pragma unroll
    for (int j = 0; j < 4; j++) acc[i][j] = fx4{0.f, 0.f, 0.f, 0.f};

  for (int k0 = 0; k0 < K; k0 += 32) {
#pragma unroll
    for (int ch = 0; ch < 2; ch++) {
      const int t = tid + ch * 256;          // 16B chunk id; row=t/4, col=(t%4)*8
      const int r = t >> 2, c = (t & 3) << 3;
      const ushort* ga = A + (size_t)(m0 + r) * K + (k0 + c);
      ushort* la = As + (size_t)(ch * 256 + w * 64) * 8;
      __builtin_amdgcn_global_load_lds((const __attribute__((address_space(1))) void*)ga,
                                       (__attribute__((address_space(3))) void*)la, 16, 0, 0);
      const ushort* gb = BT + (size_t)(n0 + r) * K + (k0 + c);
      ushort* lb = Bs + (size_t)(ch * 256 + w * 64) * 8;
      __builtin_amdgcn_global_load_lds((const __attribute__((address_space(1))) void*)gb,
                                       (__attribute__((address_space(3))) void*)lb, 16, 0, 0);
    }
    __syncthreads();
    bfx8 af[4], bfr[4];
#pragma unroll
    for (int i = 0; i < 4; i++) {
      af[i]  = *(const bfx8*)(As + ((wr * 64 + i * 16 + (l & 15)) * 32 + ((l >> 4) * 8)));
      bfr[i] = *(const bfx8*)(Bs + ((wc * 64 + i * 16 + (l & 15)) * 32 + ((l >> 4) * 8)));
    }
#pragma unroll
    for (int i = 0; i < 4; i++)
#pragma unroll
      for (int j = 0; j < 4; j++)
        acc[i][j] = __builtin_amdgcn_mfma_f32_16x16x32_bf16(af[i], bfr[j], acc[i][j], 0, 0, 0);
    __syncthreads();
  }
#pragma unroll
  for (int i = 0; i < 4; i++) {
    const int rbase = m0 + wr * 64 + i * 16 + ((l >> 4) << 2);
#pragma unroll
    for (int j = 0; j < 4; j++) {
      const int col = n0 + wc * 64 + j * 16 + (l & 15);
      const float bz = bias[col];
#pragma unroll
      for (int r2 = 0; r2 < 4; r2++) {
        const int row = rbase + r2;
        if (row < N_NODES) C[(size_t)row * 256 + col] = f2bf(acc[i][j][r2] + bz);
      }
    }
  }
}

// ---------------- GATv2 aggregation: 4 edges/wave, no-max softmax, pk-fp32 math ----------------
__global__ __launch_bounds__(256) void se_agg(const uint4* __restrict__ xlxr4,
                                              const uint* __restrict__ csrp,
                                              const int* __restrict__ offs, const int* __restrict__ deg,
                                              const float* __restrict__ eetab,
                                              const float* __restrict__ att,
                                              const float* __restrict__ bias,
                                              float* __restrict__ y, float* __restrict__ partial) {
  __shared__ ushort ee[64 * HID];         // bf16, rows >= NREL zeroed (sentinel)
  __shared__ float bstat[256];
  const int tid = threadIdx.x, w = tid >> 6, l = tid & 63;
  const int g = l >> 4, k = l & 15;       // group (edge slot), lane-in-group (8 channels)
  for (int i = tid; i < 64 * HID; i += 256) {
    const int r = i >> 7;
    ee[i] = (r < NREL) ? f2bf(eetab[i]) : (ushort)0;
  }
  bstat[tid] = 0.f;
  __syncthreads();
  // per-lane constants for channels k*8 .. k*8+7 (head = k>>1); att pre-scaled by log2(e)
  v2f av[4], bv[4];
  {
    const float* ap = att + (k >> 1) * NCH + (k & 1) * 8;
    const float* bp = bias + k * 8;
#pragma unroll
    for (int q = 0; q < 4; q++) {
      av[q] = v2f{ap[2 * q] * L2E, ap[2 * q + 1] * L2E};
      bv[q] = v2f{bp[2 * q], bp[2 * q + 1]};
    }
  }
  v2f sv[4], qv[4];
#pragma unroll
  for (int q = 0; q < 4; q++) { sv[q] = v2f{0.f, 0.f}; qv[q] = v2f{0.f, 0.f}; }
  const v2f zero = v2f{0.f, 0.f};

  const int stride = gridDim.x * 4;
  for (int n = blockIdx.x * 4 + w; n < N_NODES; n += stride) {
    const int rs = offs[n];
    const int nit = (deg[n] + 3) >> 2;
    v2f xrv[4];
    {
      const uint4 xru = xlxr4[(uint)n * 32u + 16u + (uint)k];
      xrv[0] = up2(xru.x); xrv[1] = up2(xru.y); xrv[2] = up2(xru.z); xrv[3] = up2(xru.w);
    }
    float den = 0.f;
    v2f acc[4];
#pragma unroll
    for (int q = 0; q < 4; q++) acc[q] = zero;

    uint eA = SENT, eB = SENT;
    uint4 xlv = uint4{0u, 0u, 0u, 0u};
    if (nit > 0) {
      eA = csrp[rs + g];
      xlv = xlxr4[(eA & 0xFFFFFu) * 32u + (uint)k];
      if (nit > 1) eB = csrp[rs + 4 + g];
    }
    for (int i = 0; i < nit; ++i) {
      const uint ec = eA;
      const uint4 xc = xlv;
      eA = eB;
      if (i + 1 < nit) xlv = xlxr4[(eA & 0xFFFFFu) * 32u + (uint)k];   // gather for i+1
      if (i + 2 < nit) eB = csrp[rs + 4 * (i + 2) + g];                // csr for i+2
      const uint rel = ec >> 20;
      const uint4 eeu = *(const uint4*)(ee + rel * HID + k * 8);
      v2f xls[4];
      v2f sd = zero;
      {
        const uint xcu[4] = {xc.x, xc.y, xc.z, xc.w};
        const uint eu[4] = {eeu.x, eeu.y, eeu.z, eeu.w};
#pragma unroll
        for (int q = 0; q < 4; q++) {
          const v2f xl = up2(xcu[q]);
          v2f m = xl + xrv[q] + up2(eu[q]);
          const v2f lk = __builtin_elementwise_max(m, zero) +
                         NEG_SLOPE * __builtin_elementwise_min(m, zero);
          sd += lk * av[q];
          xls[q] = xl;
        }
      }
      float s = sd.x + sd.y;
      s += __shfl_xor(s, 1);               // full 16-ch head dot across lane pair
      s = (ec >= SENT_MIN) ? -1e30f : s;   // sentinel -> p = 0
      const float p = exp2f(s);
      den += p;
      const v2f pp = v2f{p, p};
#pragma unroll
      for (int q = 0; q < 4; q++) acc[q] += pp * xls[q];
    }
    // sum groups (no exp-weighting needed: global exp domain)
    den += __shfl_xor(den, 16);
    den += __shfl_xor(den, 32);
#pragma unroll
    for (int q = 0; q < 4; q++) {
      acc[q].x += __shfl_xor(acc[q].x, 16); acc[q].x += __shfl_xor(acc[q].x, 32);
      acc[q].y += __shfl_xor(acc[q].y, 16); acc[q].y += __shfl_xor(acc[q].y, 32);
    }
    if (g == 0) {
      const float r = 1.f / fmaxf(den, 1e-16f);
      const v2f rr = v2f{r, r};
      v2f ov[4];
#pragma unroll
      for (int q = 0; q < 4; q++) {
        ov[q] = __builtin_elementwise_max(acc[q] * rr + bv[q], zero);
        sv[q] += ov[q];
        qv[q] += ov[q] * ov[q];
      }
      float4* yp = (float4*)y + (size_t)n * 32 + (size_t)k * 2;
      yp[0] = make_float4(ov[0].x, ov[0].y, ov[1].x, ov[1].y);
      yp[1] = make_float4(ov[2].x, ov[2].y, ov[3].x, ov[3].y);
    }
  }
  if (l < 16) {
#pragma unroll
    for (int q = 0; q < 4; q++) {
      unsafeAtomicAdd(&bstat[k * 8 + 2 * q], sv[q].x);
      unsafeAtomicAdd(&bstat[k * 8 + 2 * q + 1], sv[q].y);
      unsafeAtomicAdd(&bstat[128 + k * 8 + 2 * q], qv[q].x);
      unsafeAtomicAdd(&bstat[128 + k * 8 + 2 * q + 1], qv[q].y);
    }
  }
  __syncthreads();
  partial[(size_t)tid * AGG_BLOCKS + blockIdx.x] = bstat[tid];
}

// ---------------- BN stats finalize: mean + rsqrt(var+eps) per channel ----------------
__global__ __launch_bounds__(256) void se_stats(const float* __restrict__ partial, float* __restrict__ musig) {
  __shared__ float red[256];
  const int ch = blockIdx.x, tid = threadIdx.x;
  float s = 0.f;
  for (int i = tid; i < AGG_BLOCKS; i += 256) s += partial[ch * AGG_BLOCKS + i];
  red[tid] = s; __syncthreads();
  for (int o = 128; o > 0; o >>= 1) { if (tid < o) red[tid] += red[tid + o]; __syncthreads(); }
  const float sum = red[0]; __syncthreads();
  float q = 0.f;
  for (int i = tid; i < AGG_BLOCKS; i += 256) q += partial[(128 + ch) * AGG_BLOCKS + i];
  red[tid] = q; __syncthreads();
  for (int o = 128; o > 0; o >>= 1) { if (tid < o) red[tid] += red[tid + o]; __syncthreads(); }
  if (tid == 0) {
    const float mean = sum / (float)N_NODES;
    const float var = red[0] / (float)N_NODES - mean * mean;
    musig[ch] = mean;
    musig[128 + ch] = rsqrtf(var + EPS_BN);
  }
}

// ---------------- BN apply (+ bf16 residual), y fp32 in; h bf16 in/out ----------------
__global__ void se_bn(const float* __restrict__ y, const float* __restrict__ musig,
                      const float* __restrict__ gamma, const float* __restrict__ beta,
                      ushort* __restrict__ h_bf, int residual) {
  int idx = blockIdx.x * 256 + threadIdx.x;     // one uint4 = 8 channels
  if (idx >= N_NODES * 16) return;
  const int k = idx & 15;                       // ch = k*8
  const float4 y0 = ((const float4*)y)[(size_t)idx * 2];
  const float4 y1 = ((const float4*)y)[(size_t)idx * 2 + 1];
  const float4 mu0 = ((const float4*)musig)[k * 2],         mu1 = ((const float4*)musig)[k * 2 + 1];
  const float4 rs0 = ((const float4*)(musig + 128))[k * 2], rs1 = ((const float4*)(musig + 128))[k * 2 + 1];
  const float4 g0  = ((const float4*)gamma)[k * 2],         g1  = ((const float4*)gamma)[k * 2 + 1];
  const float4 b0  = ((const float4*)beta)[k * 2],          b1  = ((const float4*)beta)[k * 2 + 1];
  float v[8];
  v[0] = g0.x * (y0.x - mu0.x) * rs0.x + b0.x;
  v[1] = g0.y * (y0.y - mu0.y) * rs0.y + b0.y;
  v[2] = g0.z * (y0.z - mu0.z) * rs0.z + b0.z;
  v[3] = g0.w * (y0.w - mu0.w) * rs0.w + b0.w;
  v[4] = g1.x * (y1.x - mu1.x) * rs1.x + b1.x;
  v[5] = g1.y * (y1.y - mu1.y) * rs1.y + b1.y;
  v[6] = g1.z * (y1.z - mu1.z) * rs1.z + b1.z;
  v[7] = g1.w * (y1.w - mu1.w) * rs1.w + b1.w;
  if (residual) {
    const uint4 ho = ((const uint4*)h_bf)[idx];
    float f[8];
    unpack8(ho, f);
#pragma unroll
    for (int j = 0; j < 8; j++) v[j] += f[j];
  }
  uint4 p4;
  p4.x = ((uint)f2bf(v[1]) << 16) | f2bf(v[0]);
  p4.y = ((uint)f2bf(v[3]) << 16) | f2bf(v[2]);
  p4.z = ((uint)f2bf(v[5]) << 16) | f2bf(v[4]);
  p4.w = ((uint)f2bf(v[7]) << 16) | f2bf(v[6]);
  ((uint4*)h_bf)[idx] = p4;
}

// ---------------- mean pool by (sorted) batch, bf16 h ----------------
__global__ __launch_bounds__(256) void se_pool(const ushort* __restrict__ h_bf,
                                               const int* __restrict__ batch, float* __restrict__ pool) {
  __shared__ float ps[NGRAPH * HID];
  __shared__ float pc[NGRAPH];
  const int tid = threadIdx.x, w = tid >> 6, l = tid & 63;
  for (int i = tid; i < NGRAPH * HID; i += 256) ps[i] = 0.f;
  if (tid < NGRAPH) pc[tid] = 0.f;
  __syncthreads();
  const int chunk = (N_NODES + gridDim.x - 1) / gridDim.x;
  const int start = blockIdx.x * chunk;
  const int end = min(N_NODES, start + chunk);
  for (int n = start + w; n < end; n += 4) {
    const int gg = batch[n];
    const uint u = ((const uint*)h_bf)[(size_t)n * 64 + l];
    unsafeAtomicAdd(&ps[gg * HID + 2 * l], bf2f(u & 0xffffu));
    unsafeAtomicAdd(&ps[gg * HID + 2 * l + 1], __uint_as_float(u & 0xffff0000u));
    if (l == 0) unsafeAtomicAdd(&pc[gg], 1.f);
  }
  __syncthreads();
  for (int i = tid; i < NGRAPH * HID; i += 256) {
    const float v = ps[i];
    if (v != 0.f) unsafeAtomicAdd(&pool[i], v);
  }
  if (tid < NGRAPH) {
    const float v = pc[tid];
    if (v != 0.f) unsafeAtomicAdd(&pool[NGRAPH * HID + tid], v);
  }
}
__global__ void se_poolfin(const float* __restrict__ pool, float* __restrict__ out) {
  int idx = blockIdx.x * 256 + threadIdx.x;
  if (idx < NGRAPH * HID) {
    int g = idx >> 7;
    out[idx] = pool[idx] / fmaxf(pool[NGRAPH * HID + g], 1.f);
  }
}

extern "C" void kernel_launch(void* const* d_in, const int* in_sizes, int n_in,
                              void* d_out, int out_size, void* d_ws, size_t ws_size,
                              hipStream_t stream) {
  (void)in_sizes; (void)n_in; (void)out_size; (void)ws_size;
  const int*   tok_id  = (const int*)d_in[0];
  const float* bbox    = (const float*)d_in[1];
  const int*   ei      = (const int*)d_in[2];
  const int*   eattr   = (const int*)d_in[3];
  const int*   batch   = (const int*)d_in[4];
  const float* tok_emb = (const float*)d_in[5];
  const float* bbox_W  = (const float*)d_in[6];
  const float* bbox_b  = (const float*)d_in[7];
  const float* rel_emb = (const float*)d_in[8];
  const float* Wl0  = (const float*)d_in[9];
  const float* bl0  = (const float*)d_in[10];
  const float* Wr0  = (const float*)d_in[11];
  const float* br0  = (const float*)d_in[12];
  const float* We0  = (const float*)d_in[13];
  const float* att0 = (const float*)d_in[14];
  const float* bias0  = (const float*)d_in[15];
  const float* gamma0 = (const float*)d_in[16];
  const float* beta0  = (const float*)d_in[17];
  const float* WlS  = (const float*)d_in[18];
  const float* blS  = (const float*)d_in[19];
  const float* WrS  = (const float*)d_in[20];
  const float* brS  = (const float*)d_in[21];
  const float* WeS  = (const float*)d_in[22];
  const float* attS = (const float*)d_in[23];
  const float* biasS  = (const float*)d_in[24];
  const float* gammaS = (const float*)d_in[25];
  const float* betaS  = (const float*)d_in[26];
  float* out = (float*)d_out;

  char* ws = (char*)d_ws;
  size_t off = 0;
  auto alloc = [&](size_t bytes) -> char* {
    char* p = ws + off;
    off = (off + bytes + 255) & ~(size_t)255;
    return p;
  };
  ushort* x_bf = (ushort*)alloc((size_t)N_PAD * IN0 * 2);  // 57.7MB; reused as y (fp32, 51.2MB)
  float*  y    = (float*)x_bf;
  ushort* xlxr = (ushort*)alloc((size_t)N_PAD * 256 * 2);
  ushort* h_bf = (ushort*)alloc((size_t)N_PAD * HID * 2);
  ushort* W0T  = (ushort*)alloc((size_t)256 * IN0 * 2);
  ushort* WST  = (ushort*)alloc((size_t)2 * 256 * HID * 2);
  float*  eetab   = (float*)alloc((size_t)3 * NREL * HID * 4);
  float*  biascat = (float*)alloc((size_t)3 * 256 * 4);
  int* deg  = (int*)alloc((size_t)N_NODES * 4);
  int* offs = (int*)alloc((size_t)(N_NODES + 1) * 4);
  int* cur  = (int*)alloc((size_t)N_NODES * 4);
  int* bsum = (int*)alloc(128 * 4);
  uint* csrp = (uint*)alloc((size_t)(N_EDGES + 3 * N_NODES + 256) * 4);
  float* partial = (float*)alloc((size_t)256 * AGG_BLOCKS * 4);
  float* musig   = (float*)alloc(256 * 4);
  float* pool    = (float*)alloc((size_t)(NGRAPH * HID + NGRAPH) * 4);

  hipMemsetAsync(deg, 0, (size_t)N_NODES * 4, stream);
  hipMemsetAsync(cur, 0, (size_t)N_NODES * 4, stream);
  hipMemsetAsync(pool, 0, (size_t)(NGRAPH * HID + NGRAPH) * 4, stream);

  se_prep<<<624, 256, 0, stream>>>(Wl0, Wr0, WlS, WrS, rel_emb, We0, WeS,
                                   bl0, br0, blS, brS, W0T, WST, eetab, biascat);
  se_build_x<<<(N_PAD * 36 + 255) / 256, 256, 0, stream>>>(tok_id, bbox, tok_emb, bbox_W, bbox_b, x_bf);
  se_hist<<<(N_EDGES + 255) / 256, 256, 0, stream>>>(ei, deg);
  se_scanA<<<98, 1024, 0, stream>>>(deg, offs, bsum);
  se_scanB<<<1, 128, 0, stream>>>(bsum, 98);
  se_scanC<<<98, 1024, 0, stream>>>(offs, bsum);
  se_padfill<<<(N_NODES + 255) / 256, 256, 0, stream>>>(deg, offs, csrp);
  se_scatter<<<(N_EDGES + 255) / 256, 256, 0, stream>>>(ei, eattr, offs, cur, csrp);

  // layer 0 (K=288)
  se_gemm<IN0><<<dim3(N_PAD / 128, 2), 256, 0, stream>>>(x_bf, W0T, biascat, xlxr);
  se_agg<<<AGG_BLOCKS, 256, 0, stream>>>((const uint4*)xlxr, csrp, offs, deg,
                                         eetab, att0, bias0, y, partial);
  se_stats<<<128, 256, 0, stream>>>(partial, musig);
  se_bn<<<(N_NODES * 16 + 255) / 256, 256, 0, stream>>>(y, musig, gamma0, beta0, h_bf, 0);

  // layers 1..2 (K=128)
  for (int li = 0; li < 2; ++li) {
    se_gemm<HID><<<dim3(N_PAD / 128, 2), 256, 0, stream>>>(h_bf, WST + (size_t)li * 256 * HID,
                                                           biascat + (li + 1) * 256, xlxr);
    se_agg<<<AGG_BLOCKS, 256, 0, stream>>>((const uint4*)xlxr, csrp, offs, deg,
                                           eetab + (size_t)(li + 1) * NREL * HID,
                                           attS + (size_t)li * NHEAD * NCH,
                                           biasS + (size_t)li * HID, y, partial);
    se_stats<<<128, 256, 0, stream>>>(partial, musig);
    se_bn<<<(N_NODES * 16 + 255) / 256, 256, 0, stream>>>(y, musig, gammaS + (size_t)li * HID,
                                                          betaS + (size_t)li * HID, h_bf, 1);
  }

  se_pool<<<POOL_BLOCKS, 256, 0, stream>>>(h_bf, batch, pool);
  se_poolfin<<<32, 256, 0, stream>>>(pool, out);
}

// Round 4
// 864.110 us; speedup vs baseline: 1.5887x; 1.1161x over previous
//
#include <hip/hip_runtime.h>

#define N_NODES 100000
#define N_PAD   100096
#define N_EDGES 1600000
#define NGRAPH  64
#define NHEAD   8
#define NCH     16
#define HID     128
#define IN0     288
#define NREL    51
#define EMB     256
#define NBBOX   32
#define NEG_SLOPE 0.2f
#define EPS_BN  1e-5f
#define AGG_BLOCKS 2048
#define POOL_BLOCKS 1024
#define SENT 0x03F00000u          /* rel=63, src=0 */
#define SENT_MIN ((uint)(NREL) << 20)
#define L2E 1.4426950408889634f

typedef unsigned int uint;
typedef unsigned short ushort;

typedef __bf16 bf16_t;
typedef bf16_t bfx8 __attribute__((ext_vector_type(8)));
typedef float  fx4  __attribute__((ext_vector_type(4)));
typedef float  v2f  __attribute__((ext_vector_type(2)));

__device__ __forceinline__ ushort f2bf(float f) {
  uint u = __float_as_uint(f);
  u += 0x7fffu + ((u >> 16) & 1u);
  return (ushort)(u >> 16);
}
__device__ __forceinline__ float bf2f(uint u) { return __uint_as_float(u << 16); }
__device__ __forceinline__ v2f up2(uint u) {
  v2f r;
  r.x = __uint_as_float(u << 16);
  r.y = __uint_as_float(u & 0xffff0000u);
  return r;
}
__device__ __forceinline__ void unpack8(uint4 u, float* f) {
  f[0] = __uint_as_float(u.x << 16); f[1] = __uint_as_float(u.x & 0xffff0000u);
  f[2] = __uint_as_float(u.y << 16); f[3] = __uint_as_float(u.y & 0xffff0000u);
  f[4] = __uint_as_float(u.z << 16); f[5] = __uint_as_float(u.z & 0xffff0000u);
  f[6] = __uint_as_float(u.w << 16); f[7] = __uint_as_float(u.w & 0xffff0000u);
}

// ---------------- prep: weight transpose->bf16, ee tables, bias concat ----------------
__global__ void se_prep(const float* __restrict__ Wl0, const float* __restrict__ Wr0,
                        const float* __restrict__ WlS, const float* __restrict__ WrS,
                        const float* __restrict__ rel_emb, const float* __restrict__ We0,
                        const float* __restrict__ WeS,
                        const float* __restrict__ bl0, const float* __restrict__ br0,
                        const float* __restrict__ blS, const float* __restrict__ brS,
                        ushort* __restrict__ W0T, ushort* __restrict__ WST,
                        float* __restrict__ eetab, float* __restrict__ biascat) {
  int i = blockIdx.x * 256 + threadIdx.x;
  if (i < 256 * IN0) {                       // W0T[j][k] = Wl0|Wr0 [k][j]
    int j = i / IN0, k = i - j * IN0;
    float v = (j < 128) ? Wl0[k * 128 + j] : Wr0[k * 128 + (j - 128)];
    W0T[j * IN0 + k] = f2bf(v);
    return;
  }
  i -= 256 * IN0;
  if (i < 2 * 256 * HID) {                   // WST[l][j][k]
    int li = i >> 15;
    int rem = i & 32767;
    int j = rem >> 7, k = rem & 127;
    float v = (j < 128) ? WlS[(li * 128 + k) * 128 + j] : WrS[(li * 128 + k) * 128 + (j - 128)];
    WST[(li * 256 + j) * 128 + k] = f2bf(v);
    return;
  }
  i -= 2 * 256 * HID;
  if (i < 3 * NREL * HID) {                  // eetab[l][r][j] = sum_c rel[r][c]*We_l[c][j]
    int li = i / (NREL * HID);
    int rem = i - li * (NREL * HID);
    int r = rem >> 7, j = rem & 127;
    const float* We = (li == 0) ? We0 : (WeS + (li - 1) * NCH * HID);
    float s = 0.f;
#pragma unroll
    for (int c = 0; c < NCH; c++) s += rel_emb[r * NCH + c] * We[c * HID + j];
    eetab[li * (NREL * HID) + rem] = s;
    return;
  }
  i -= 3 * NREL * HID;
  if (i < 3 * 256) {                         // biascat[l][256] = bl|br
    int li = i >> 8, j = i & 255;
    const float* bl = (li == 0) ? bl0 : (blS + (li - 1) * HID);
    const float* br = (li == 0) ? br0 : (brS + (li - 1) * HID);
    biascat[i] = (j < 128) ? bl[j] : br[j - 128];
  }
}

// ---------------- build x = [tok_emb[tok] | bbox@W+b] as bf16 (8ch/thread), zero-pad rows ----------------
__global__ void se_build_x(const int* __restrict__ tok_id, const float* __restrict__ bbox,
                           const float* __restrict__ tok_emb, const float* __restrict__ bbox_W,
                           const float* __restrict__ bbox_b, ushort* __restrict__ x) {
  int idx = blockIdx.x * 256 + threadIdx.x;   // one uint4 = 8 channels
  if (idx >= N_PAD * 36) return;
  int n = idx / 36, c = (idx - n * 36) * 8;
  float f[8];
  if (n >= N_NODES) {
#pragma unroll
    for (int j = 0; j < 8; j++) f[j] = 0.f;
  } else if (c < EMB) {
    const float* te = tok_emb + (size_t)tok_id[n] * EMB + c;
    const float4 t0 = *(const float4*)te, t1 = *(const float4*)(te + 4);
    f[0] = t0.x; f[1] = t0.y; f[2] = t0.z; f[3] = t0.w;
    f[4] = t1.x; f[5] = t1.y; f[6] = t1.z; f[7] = t1.w;
  } else {
    const int j0 = c - EMB;
    const float4 bb = *(const float4*)(bbox + (size_t)n * 4);
#pragma unroll
    for (int j = 0; j < 8; j++) {
      float v = bbox_b[j0 + j];
      v += bb.x * bbox_W[0 * NBBOX + j0 + j];
      v += bb.y * bbox_W[1 * NBBOX + j0 + j];
      v += bb.z * bbox_W[2 * NBBOX + j0 + j];
      v += bb.w * bbox_W[3 * NBBOX + j0 + j];
      f[j] = v;
    }
  }
  uint4 p;
  p.x = ((uint)f2bf(f[1]) << 16) | f2bf(f[0]);
  p.y = ((uint)f2bf(f[3]) << 16) | f2bf(f[2]);
  p.z = ((uint)f2bf(f[5]) << 16) | f2bf(f[4]);
  p.w = ((uint)f2bf(f[7]) << 16) | f2bf(f[6]);
  ((uint4*)x)[idx] = p;
}

// ---------------- CSR build (rows padded to multiples of 4, sentinel-filled) ----------------
__global__ void se_hist(const int* __restrict__ ei, int* __restrict__ deg) {
  int e = blockIdx.x * 256 + threadIdx.x;
  if (e < N_EDGES) atomicAdd(&deg[ei[N_EDGES + e]], 1);
}
__global__ __launch_bounds__(1024) void se_scanA(const int* __restrict__ deg,
                                                 int* __restrict__ offs, int* __restrict__ bsum) {
  __shared__ int s[1024];
  const int tid = threadIdx.x;
  const int i = blockIdx.x * 1024 + tid;
  int v = (i < N_NODES) ? ((deg[i] + 3) & ~3) : 0;   // padded degree
  s[tid] = v;
  __syncthreads();
  for (int d = 1; d < 1024; d <<= 1) {
    int t = (tid >= d) ? s[tid - d] : 0;
    __syncthreads();
    s[tid] += t;
    __syncthreads();
  }
  if (i < N_NODES) offs[i] = s[tid] - v;
  if (tid == 1023) bsum[blockIdx.x] = s[1023];
}
__global__ __launch_bounds__(128) void se_scanB(int* __restrict__ bsum, int nb) {
  __shared__ int s[128];
  const int t = threadIdx.x;
  int v = (t < nb) ? bsum[t] : 0;
  s[t] = v;
  __syncthreads();
  for (int d = 1; d < 128; d <<= 1) {
    int u = (t >= d) ? s[t - d] : 0;
    __syncthreads();
    s[t] += u;
    __syncthreads();
  }
  if (t < nb) bsum[t] = s[t] - v;   // exclusive
}
__global__ __launch_bounds__(1024) void se_scanC(int* __restrict__ offs, const int* __restrict__ bsum) {
  int i = blockIdx.x * 1024 + threadIdx.x;
  if (i < N_NODES) offs[i] += bsum[blockIdx.x];
}
__global__ void se_padfill(const int* __restrict__ deg, const int* __restrict__ offs,
                           uint* __restrict__ csrp) {
  int n = blockIdx.x * 256 + threadIdx.x;
  if (n >= N_NODES) return;
  const int d = deg[n];
  const int s = offs[n] + d;
  const int c = ((d + 3) & ~3) - d;
  for (int j = 0; j < c; j++) csrp[s + j] = SENT;
}
__global__ void se_scatter(const int* __restrict__ ei, const int* __restrict__ eattr,
                           const int* __restrict__ offs, int* __restrict__ cur,
                           uint* __restrict__ csrp) {
  int e = blockIdx.x * 256 + threadIdx.x;
  if (e < N_EDGES) {
    int d = ei[N_EDGES + e];
    int p = offs[d] + atomicAdd(&cur[d], 1);
    csrp[p] = (uint)ei[e] | ((uint)eattr[e] << 20);
  }
}

// ---------------- GEMM: C[N,256] = A[N,K] @ BT[256,K]^T + biascat, bf16 in/out, fp32 acc ----------------
template <int K>
__global__ __launch_bounds__(256) void se_gemm(const ushort* __restrict__ A,
                                               const ushort* __restrict__ BT,
                                               const float* __restrict__ bias,
                                               ushort* __restrict__ C) {
  __shared__ __align__(16) ushort As[128 * 32];
  __shared__ __align__(16) ushort Bs[128 * 32];
  const int tid = threadIdx.x;
  const int w = tid >> 6, l = tid & 63;
  const int wr = w >> 1, wc = w & 1;
  const int m0 = blockIdx.x * 128, n0 = blockIdx.y * 128;
  fx4 acc[4][4];
#pragma unroll
  for (int i = 0; i < 4; i++)
#pragma unroll
    for (int j = 0; j < 4; j++) acc[i][j] = fx4{0.f, 0.f, 0.f, 0.f};

  for (int k0 = 0; k0 < K; k0 += 32) {
#pragma unroll
    for (int ch = 0; ch < 2; ch++) {
      const int t = tid + ch * 256;          // 16B chunk id; row=t/4, col=(t%4)*8
      const int r = t >> 2, c = (t & 3) << 3;
      const ushort* ga = A + (size_t)(m0 + r) * K + (k0 + c);
      ushort* la = As + (size_t)(ch * 256 + w * 64) * 8;
      __builtin_amdgcn_global_load_lds((const __attribute__((address_space(1))) void*)ga,
                                       (__attribute__((address_space(3))) void*)la, 16, 0, 0);
      const ushort* gb = BT + (size_t)(n0 + r) * K + (k0 + c);
      ushort* lb = Bs + (size_t)(ch * 256 + w * 64) * 8;
      __builtin_amdgcn_global_load_lds((const __attribute__((address_space(1))) void*)gb,
                                       (__attribute__((address_space(3))) void*)lb, 16, 0, 0);
    }
    __syncthreads();
    bfx8 af[4], bfr[4];
#pragma unroll
    for (int i = 0; i < 4; i++) {
      af[i]  = *(const bfx8*)(As + ((wr * 64 + i * 16 + (l & 15)) * 32 + ((l >> 4) * 8)));
      bfr[i] = *(const bfx8*)(Bs + ((wc * 64 + i * 16 + (l & 15)) * 32 + ((l >> 4) * 8)));
    }
#pragma unroll
    for (int i = 0; i < 4; i++)
#pragma unroll
      for (int j = 0; j < 4; j++)
        acc[i][j] = __builtin_amdgcn_mfma_f32_16x16x32_bf16(af[i], bfr[j], acc[i][j], 0, 0, 0);
    __syncthreads();
  }
#pragma unroll
  for (int i = 0; i < 4; i++) {
    const int rbase = m0 + wr * 64 + i * 16 + ((l >> 4) << 2);
#pragma unroll
    for (int j = 0; j < 4; j++) {
      const int col = n0 + wc * 64 + j * 16 + (l & 15);
      const float bz = bias[col];
#pragma unroll
      for (int r2 = 0; r2 < 4; r2++) {
        const int row = rbase + r2;
        if (row < N_NODES) C[(size_t)row * 256 + col] = f2bf(acc[i][j][r2] + bz);
      }
    }
  }
}

// ---------------- GATv2 aggregation: 4 edges/wave, no-max softmax, pk-fp32 math ----------------
__global__ __launch_bounds__(256) void se_agg(const uint4* __restrict__ xlxr4,
                                              const uint* __restrict__ csrp,
                                              const int* __restrict__ offs, const int* __restrict__ deg,
                                              const float* __restrict__ eetab,
                                              const float* __restrict__ att,
                                              const float* __restrict__ bias,
                                              float* __restrict__ y, float* __restrict__ partial) {
  __shared__ ushort ee[64 * HID];         // bf16, rows >= NREL zeroed (sentinel)
  __shared__ float bstat[256];
  const int tid = threadIdx.x, w = tid >> 6, l = tid & 63;
  const int g = l >> 4, k = l & 15;       // group (edge slot), lane-in-group (8 channels)
  for (int i = tid; i < 64 * HID; i += 256) {
    const int r = i >> 7;
    ee[i] = (r < NREL) ? f2bf(eetab[i]) : (ushort)0;
  }
  bstat[tid] = 0.f;
  __syncthreads();
  // per-lane constants for channels k*8 .. k*8+7 (head = k>>1); att pre-scaled by log2(e)
  v2f av[4], bv[4];
  {
    const float* ap = att + (k >> 1) * NCH + (k & 1) * 8;
    const float* bp = bias + k * 8;
#pragma unroll
    for (int q = 0; q < 4; q++) {
      av[q] = v2f{ap[2 * q] * L2E, ap[2 * q + 1] * L2E};
      bv[q] = v2f{bp[2 * q], bp[2 * q + 1]};
    }
  }
  v2f sv[4], qv[4];
#pragma unroll
  for (int q = 0; q < 4; q++) { sv[q] = v2f{0.f, 0.f}; qv[q] = v2f{0.f, 0.f}; }
  const v2f zero = v2f{0.f, 0.f};

  const int stride = gridDim.x * 4;
  for (int n = blockIdx.x * 4 + w; n < N_NODES; n += stride) {
    const int rs = offs[n];
    const int nit = (deg[n] + 3) >> 2;
    v2f xrv[4];
    {
      const uint4 xru = xlxr4[(uint)n * 32u + 16u + (uint)k];
      xrv[0] = up2(xru.x); xrv[1] = up2(xru.y); xrv[2] = up2(xru.z); xrv[3] = up2(xru.w);
    }
    float den = 0.f;
    v2f acc[4];
#pragma unroll
    for (int q = 0; q < 4; q++) acc[q] = zero;

    uint eA = SENT, eB = SENT;
    uint4 xlv = uint4{0u, 0u, 0u, 0u};
    if (nit > 0) {
      eA = csrp[rs + g];
      xlv = xlxr4[(eA & 0xFFFFFu) * 32u + (uint)k];
      if (nit > 1) eB = csrp[rs + 4 + g];
    }
    for (int i = 0; i < nit; ++i) {
      const uint ec = eA;
      const uint4 xc = xlv;
      eA = eB;
      if (i + 1 < nit) xlv = xlxr4[(eA & 0xFFFFFu) * 32u + (uint)k];   // gather for i+1
      if (i + 2 < nit) eB = csrp[rs + 4 * (i + 2) + g];                // csr for i+2
      const uint rel = ec >> 20;
      const uint4 eeu = *(const uint4*)(ee + rel * HID + k * 8);
      v2f xls[4];
      v2f sd = zero;
      {
        const uint xcu[4] = {xc.x, xc.y, xc.z, xc.w};
        const uint eu[4] = {eeu.x, eeu.y, eeu.z, eeu.w};
#pragma unroll
        for (int q = 0; q < 4; q++) {
          const v2f xl = up2(xcu[q]);
          v2f m = xl + xrv[q] + up2(eu[q]);
          const v2f lk = __builtin_elementwise_max(m, zero) +
                         NEG_SLOPE * __builtin_elementwise_min(m, zero);
          sd += lk * av[q];
          xls[q] = xl;
        }
      }
      float s = sd.x + sd.y;
      s += __shfl_xor(s, 1);               // full 16-ch head dot across lane pair
      s = (ec >= SENT_MIN) ? -1e30f : s;   // sentinel -> p = 0
      const float p = exp2f(s);
      den += p;
      const v2f pp = v2f{p, p};
#pragma unroll
      for (int q = 0; q < 4; q++) acc[q] += pp * xls[q];
    }
    // sum groups (no exp-weighting needed: global exp domain)
    den += __shfl_xor(den, 16);
    den += __shfl_xor(den, 32);
#pragma unroll
    for (int q = 0; q < 4; q++) {
      acc[q].x += __shfl_xor(acc[q].x, 16); acc[q].x += __shfl_xor(acc[q].x, 32);
      acc[q].y += __shfl_xor(acc[q].y, 16); acc[q].y += __shfl_xor(acc[q].y, 32);
    }
    if (g == 0) {
      const float r = 1.f / fmaxf(den, 1e-16f);
      const v2f rr = v2f{r, r};
      v2f ov[4];
#pragma unroll
      for (int q = 0; q < 4; q++) {
        ov[q] = __builtin_elementwise_max(acc[q] * rr + bv[q], zero);
        sv[q] += ov[q];
        qv[q] += ov[q] * ov[q];
      }
      float4* yp = (float4*)y + (size_t)n * 32 + (size_t)k * 2;
      yp[0] = make_float4(ov[0].x, ov[0].y, ov[1].x, ov[1].y);
      yp[1] = make_float4(ov[2].x, ov[2].y, ov[3].x, ov[3].y);
    }
  }
  if (l < 16) {
#pragma unroll
    for (int q = 0; q < 4; q++) {
      unsafeAtomicAdd(&bstat[k * 8 + 2 * q], sv[q].x);
      unsafeAtomicAdd(&bstat[k * 8 + 2 * q + 1], sv[q].y);
      unsafeAtomicAdd(&bstat[128 + k * 8 + 2 * q], qv[q].x);
      unsafeAtomicAdd(&bstat[128 + k * 8 + 2 * q + 1], qv[q].y);
    }
  }
  __syncthreads();
  partial[(size_t)tid * AGG_BLOCKS + blockIdx.x] = bstat[tid];
}

// ---------------- BN stats finalize: mean + rsqrt(var+eps) per channel ----------------
__global__ __launch_bounds__(256) void se_stats(const float* __restrict__ partial, float* __restrict__ musig) {
  __shared__ float red[256];
  const int ch = blockIdx.x, tid = threadIdx.x;
  float s = 0.f;
  for (int i = tid; i < AGG_BLOCKS; i += 256) s += partial[ch * AGG_BLOCKS + i];
  red[tid] = s; __syncthreads();
  for (int o = 128; o > 0; o >>= 1) { if (tid < o) red[tid] += red[tid + o]; __syncthreads(); }
  const float sum = red[0]; __syncthreads();
  float q = 0.f;
  for (int i = tid; i < AGG_BLOCKS; i += 256) q += partial[(128 + ch) * AGG_BLOCKS + i];
  red[tid] = q; __syncthreads();
  for (int o = 128; o > 0; o >>= 1) { if (tid < o) red[tid] += red[tid + o]; __syncthreads(); }
  if (tid == 0) {
    const float mean = sum / (float)N_NODES;
    const float var = red[0] / (float)N_NODES - mean * mean;
    musig[ch] = mean;
    musig[128 + ch] = rsqrtf(var + EPS_BN);
  }
}

// ---------------- BN apply (+ bf16 residual), y fp32 in; h bf16 in/out ----------------
__global__ void se_bn(const float* __restrict__ y, const float* __restrict__ musig,
                      const float* __restrict__ gamma, const float* __restrict__ beta,
                      ushort* __restrict__ h_bf, int residual) {
  int idx = blockIdx.x * 256 + threadIdx.x;     // one uint4 = 8 channels
  if (idx >= N_NODES * 16) return;
  const int k = idx & 15;                       // ch = k*8
  const float4 y0 = ((const float4*)y)[(size_t)idx * 2];
  const float4 y1 = ((const float4*)y)[(size_t)idx * 2 + 1];
  const float4 mu0 = ((const float4*)musig)[k * 2],         mu1 = ((const float4*)musig)[k * 2 + 1];
  const float4 rs0 = ((const float4*)(musig + 128))[k * 2], rs1 = ((const float4*)(musig + 128))[k * 2 + 1];
  const float4 g0  = ((const float4*)gamma)[k * 2],         g1  = ((const float4*)gamma)[k * 2 + 1];
  const float4 b0  = ((const float4*)beta)[k * 2],          b1  = ((const float4*)beta)[k * 2 + 1];
  float v[8];
  v[0] = g0.x * (y0.x - mu0.x) * rs0.x + b0.x;
  v[1] = g0.y * (y0.y - mu0.y) * rs0.y + b0.y;
  v[2] = g0.z * (y0.z - mu0.z) * rs0.z + b0.z;
  v[3] = g0.w * (y0.w - mu0.w) * rs0.w + b0.w;
  v[4] = g1.x * (y1.x - mu1.x) * rs1.x + b1.x;
  v[5] = g1.y * (y1.y - mu1.y) * rs1.y + b1.y;
  v[6] = g1.z * (y1.z - mu1.z) * rs1.z + b1.z;
  v[7] = g1.w * (y1.w - mu1.w) * rs1.w + b1.w;
  if (residual) {
    const uint4 ho = ((const uint4*)h_bf)[idx];
    float f[8];
    unpack8(ho, f);
#pragma unroll
    for (int j = 0; j < 8; j++) v[j] += f[j];
  }
  uint4 p4;
  p4.x = ((uint)f2bf(v[1]) << 16) | f2bf(v[0]);
  p4.y = ((uint)f2bf(v[3]) << 16) | f2bf(v[2]);
  p4.z = ((uint)f2bf(v[5]) << 16) | f2bf(v[4]);
  p4.w = ((uint)f2bf(v[7]) << 16) | f2bf(v[6]);
  ((uint4*)h_bf)[idx] = p4;
}

// ---------------- mean pool: run-length register accumulation (batch sorted), global-atomic flush ----------------
__global__ __launch_bounds__(256) void se_pool(const ushort* __restrict__ h_bf,
                                               const int* __restrict__ batch,
                                               float* __restrict__ pool) {
  const int tid = threadIdx.x, w = tid >> 6, l = tid & 63;
  const int wid = blockIdx.x * 4 + w;
  const int nw = gridDim.x * 4;
  const int chunk = (N_NODES + nw - 1) / nw;
  const int start = wid * chunk;
  const int end = min(N_NODES, start + chunk);
  float a0 = 0.f, a1 = 0.f;
  int cg = -1, cnt = 0;
  for (int n = start; n < end; ++n) {
    const int gg = batch[n];
    if (gg != cg) {
      if (cg >= 0) {
        unsafeAtomicAdd(&pool[cg * HID + 2 * l], a0);
        unsafeAtomicAdd(&pool[cg * HID + 2 * l + 1], a1);
        if (l == 0) unsafeAtomicAdd(&pool[NGRAPH * HID + cg], (float)cnt);
      }
      a0 = 0.f; a1 = 0.f; cnt = 0; cg = gg;
    }
    const uint u = ((const uint*)h_bf)[(size_t)n * 64 + l];
    a0 += bf2f(u & 0xffffu);
    a1 += __uint_as_float(u & 0xffff0000u);
    cnt++;
  }
  if (cg >= 0) {
    unsafeAtomicAdd(&pool[cg * HID + 2 * l], a0);
    unsafeAtomicAdd(&pool[cg * HID + 2 * l + 1], a1);
    if (l == 0) unsafeAtomicAdd(&pool[NGRAPH * HID + cg], (float)cnt);
  }
}
__global__ void se_poolfin(const float* __restrict__ pool, float* __restrict__ out) {
  int idx = blockIdx.x * 256 + threadIdx.x;
  if (idx < NGRAPH * HID) {
    int g = idx >> 7;
    out[idx] = pool[idx] / fmaxf(pool[NGRAPH * HID + g], 1.f);
  }
}

extern "C" void kernel_launch(void* const* d_in, const int* in_sizes, int n_in,
                              void* d_out, int out_size, void* d_ws, size_t ws_size,
                              hipStream_t stream) {
  (void)in_sizes; (void)n_in; (void)out_size; (void)ws_size;
  const int*   tok_id  = (const int*)d_in[0];
  const float* bbox    = (const float*)d_in[1];
  const int*   ei      = (const int*)d_in[2];
  const int*   eattr   = (const int*)d_in[3];
  const int*   batch   = (const int*)d_in[4];
  const float* tok_emb = (const float*)d_in[5];
  const float* bbox_W  = (const float*)d_in[6];
  const float* bbox_b  = (const float*)d_in[7];
  const float* rel_emb = (const float*)d_in[8];
  const float* Wl0  = (const float*)d_in[9];
  const float* bl0  = (const float*)d_in[10];
  const float* Wr0  = (const float*)d_in[11];
  const float* br0  = (const float*)d_in[12];
  const float* We0  = (const float*)d_in[13];
  const float* att0 = (const float*)d_in[14];
  const float* bias0  = (const float*)d_in[15];
  const float* gamma0 = (const float*)d_in[16];
  const float* beta0  = (const float*)d_in[17];
  const float* WlS  = (const float*)d_in[18];
  const float* blS  = (const float*)d_in[19];
  const float* WrS  = (const float*)d_in[20];
  const float* brS  = (const float*)d_in[21];
  const float* WeS  = (const float*)d_in[22];
  const float* attS = (const float*)d_in[23];
  const float* biasS  = (const float*)d_in[24];
  const float* gammaS = (const float*)d_in[25];
  const float* betaS  = (const float*)d_in[26];
  float* out = (float*)d_out;

  char* ws = (char*)d_ws;
  size_t off = 0;
  auto alloc = [&](size_t bytes) -> char* {
    char* p = ws + off;
    off = (off + bytes + 255) & ~(size_t)255;
    return p;
  };
  ushort* x_bf = (ushort*)alloc((size_t)N_PAD * IN0 * 2);  // 57.7MB; reused as y (fp32, 51.2MB)
  float*  y    = (float*)x_bf;
  ushort* xlxr = (ushort*)alloc((size_t)N_PAD * 256 * 2);
  ushort* h_bf = (ushort*)alloc((size_t)N_PAD * HID * 2);
  ushort* W0T  = (ushort*)alloc((size_t)256 * IN0 * 2);
  ushort* WST  = (ushort*)alloc((size_t)2 * 256 * HID * 2);
  float*  eetab   = (float*)alloc((size_t)3 * NREL * HID * 4);
  float*  biascat = (float*)alloc((size_t)3 * 256 * 4);
  int* deg  = (int*)alloc((size_t)N_NODES * 4);
  int* offs = (int*)alloc((size_t)(N_NODES + 1) * 4);
  int* cur  = (int*)alloc((size_t)N_NODES * 4);
  int* bsum = (int*)alloc(128 * 4);
  uint* csrp = (uint*)alloc((size_t)(N_EDGES + 3 * N_NODES + 256) * 4);
  float* partial = (float*)alloc((size_t)256 * AGG_BLOCKS * 4);
  float* musig   = (float*)alloc(256 * 4);
  float* pool    = (float*)alloc((size_t)(NGRAPH * HID + NGRAPH) * 4);

  hipMemsetAsync(deg, 0, (size_t)N_NODES * 4, stream);
  hipMemsetAsync(cur, 0, (size_t)N_NODES * 4, stream);
  hipMemsetAsync(pool, 0, (size_t)(NGRAPH * HID + NGRAPH) * 4, stream);

  se_prep<<<624, 256, 0, stream>>>(Wl0, Wr0, WlS, WrS, rel_emb, We0, WeS,
                                   bl0, br0, blS, brS, W0T, WST, eetab, biascat);
  se_build_x<<<(N_PAD * 36 + 255) / 256, 256, 0, stream>>>(tok_id, bbox, tok_emb, bbox_W, bbox_b, x_bf);
  se_hist<<<(N_EDGES + 255) / 256, 256, 0, stream>>>(ei, deg);
  se_scanA<<<98, 1024, 0, stream>>>(deg, offs, bsum);
  se_scanB<<<1, 128, 0, stream>>>(bsum, 98);
  se_scanC<<<98, 1024, 0, stream>>>(offs, bsum);
  se_padfill<<<(N_NODES + 255) / 256, 256, 0, stream>>>(deg, offs, csrp);
  se_scatter<<<(N_EDGES + 255) / 256, 256, 0, stream>>>(ei, eattr, offs, cur, csrp);

  // layer 0 (K=288)
  se_gemm<IN0><<<dim3(N_PAD / 128, 2), 256, 0, stream>>>(x_bf, W0T, biascat, xlxr);
  se_agg<<<AGG_BLOCKS, 256, 0, stream>>>((const uint4*)xlxr, csrp, offs, deg,
                                         eetab, att0, bias0, y, partial);
  se_stats<<<128, 256, 0, stream>>>(partial, musig);
  se_bn<<<(N_NODES * 16 + 255) / 256, 256, 0, stream>>>(y, musig, gamma0, beta0, h_bf, 0);

  // layers 1..2 (K=128)
  for (int li = 0; li < 2; ++li) {
    se_gemm<HID><<<dim3(N_PAD / 128, 2), 256, 0, stream>>>(h_bf, WST + (size_t)li * 256 * HID,
                                                           biascat + (li + 1) * 256, xlxr);
    se_agg<<<AGG_BLOCKS, 256, 0, stream>>>((const uint4*)xlxr, csrp, offs, deg,
                                           eetab + (size_t)(li + 1) * NREL * HID,
                                           attS + (size_t)li * NHEAD * NCH,
                                           biasS + (size_t)li * HID, y, partial);
    se_stats<<<128, 256, 0, stream>>>(partial, musig);
    se_bn<<<(N_NODES * 16 + 255) / 256, 256, 0, stream>>>(y, musig, gammaS + (size_t)li * HID,
                                                          betaS + (size_t)li * HID, h_bf, 1);
  }

  se_pool<<<POOL_BLOCKS, 256, 0, stream>>>(h_bf, batch, pool);
  se_poolfin<<<32, 256, 0, stream>>>(pool, out);
}